// Round 1
// baseline (925.596 us; speedup 1.0000x reference)
//
#include <hip/hip_runtime.h>

#define PLANE 65536
#define WIDTH 256

// ---------------------------------------------------------------------------
// prep: V, C_new, H (Laplacian), and stage Vs = V/sf for the conv chain.
// Grid: 2048 x 256 threads over all B*H*W pixels.
// ---------------------------------------------------------------------------
__global__ __launch_bounds__(256) void prep_k(
    const float* __restrict__ inputs, const float* __restrict__ H0,
    const float* __restrict__ C0, const float* __restrict__ c2p,
    const float* __restrict__ sfp, float* __restrict__ dout,
    float* __restrict__ vs)
{
  int p = blockIdx.x * 256 + threadIdx.x;      // 0 .. 524287
  int b = p >> 16;
  int i = p & 65535;
  int y = i >> 8;
  int x = i & 255;
  float in   = inputs[p];
  float h0   = H0[p];
  float c0a  = C0[b * 131072 + i];             // C0[:,0]
  float up    = (y > 0)   ? inputs[p - 256] : 0.f;
  float down  = (y < 255) ? inputs[p + 256] : 0.f;
  float left  = (x > 0)   ? inputs[p - 1]   : 0.f;
  float right = (x < 255) ? inputs[p + 1]   : 0.f;
  float lap = up + down + left + right - 4.f * in;
  float c2 = c2p[0];
  float sf = sfp[0];
  float Hv = 2.f * in - c0a + c2 * lap;
  float V  = in - h0;
  dout[524288 + p]  = Hv;                      // H
  dout[2097152 + p] = V;                       // V
  dout[1048576 + b * 131072 + i]         = in;   // C_new[:,0]
  dout[1048576 + b * 131072 + 65536 + i] = c0a;  // C_new[:,1]
  vs[p] = V / sf;                              // conv-chain input
}

// ---------------------------------------------------------------------------
// weight transpose: w[cout][cin][3][3] -> wT[(cin*9+tap)][cout]
// so inner-loop weight reads are uniform + contiguous (-> s_load_dwordxN).
// ---------------------------------------------------------------------------
__global__ __launch_bounds__(256) void wtrans_k(
    const float* __restrict__ w1, const float* __restrict__ w2,
    const float* __restrict__ w3, float* __restrict__ w1t,
    float* __restrict__ w2t, float* __restrict__ w3t)
{
  int t = blockIdx.x * 256 + threadIdx.x;
  if (t < 288) {                       // w1: [32][1][9] -> [tap][32]
    int tap = t >> 5, cout = t & 31;
    w1t[t] = w1[cout * 9 + tap];
  }
  int t2 = t - 288;
  if (t2 >= 0 && t2 < 18432) {         // w2: [64][32][9] -> [(cin*9+tap)][64]
    int cout = t2 & 63, r = t2 >> 6;
    int cin = r / 9, tap = r % 9;
    w2t[t2] = w2[(cout * 32 + cin) * 9 + tap];
  }
  int t3 = t - (288 + 18432);
  if (t3 >= 0 && t3 < 18432) {         // w3: [32][64][9] -> [(cin*9+tap)][32]
    int cout = t3 & 31, r = t3 >> 5;
    int cin = r / 9, tap = r % 9;
    w3t[t3] = w3[(cout * 64 + cin) * 9 + tap];
  }
}

// ---------------------------------------------------------------------------
// generic 3x3 SAME conv, one image plane set: in [CIN][256][256] ->
// out [COUT][256][256]. Block = one row (256 threads = x), grid.y = cout
// groups of CPB. Weights read via uniform (scalar) loads from wT.
// ---------------------------------------------------------------------------
template<int CIN, int COUT, int CPB, bool RELU>
__global__ __launch_bounds__(256) void conv3x3_k(
    const float* __restrict__ in, const float* __restrict__ wT,
    const float* __restrict__ bias, float* __restrict__ out)
{
  const int x  = threadIdx.x;          // 0..255
  const int y  = blockIdx.x;           // 0..255
  const int cb = blockIdx.y * CPB;

  float acc[CPB];
  #pragma unroll
  for (int i = 0; i < CPB; i++) acc[i] = bias[cb + i];

  for (int c = 0; c < CIN; c++) {
    const float* ip = in + c * PLANE + y * WIDTH + x;
    float v[9];
    #pragma unroll
    for (int dy = 0; dy < 3; dy++) {
      int yy = y + dy - 1;
      bool rv = (yy >= 0 && yy < 256);
      const float* rp = ip + (dy - 1) * WIDTH;
      v[dy * 3 + 0] = (rv && x > 0)   ? rp[-1] : 0.f;
      v[dy * 3 + 1] = rv              ? rp[0]  : 0.f;
      v[dy * 3 + 2] = (rv && x < 255) ? rp[1]  : 0.f;
    }
    #pragma unroll
    for (int t = 0; t < 9; t++) {
      const float* wp = wT + (c * 9 + t) * COUT + cb;   // uniform address
      float vv = v[t];
      #pragma unroll
      for (int i = 0; i < CPB; i++) acc[i] = fmaf(wp[i], vv, acc[i]);
    }
  }
  #pragma unroll
  for (int i = 0; i < CPB; i++) {
    float r = RELU ? fmaxf(acc[i], 0.f) : acc[i];
    out[(cb + i) * PLANE + y * WIDTH + x] = r;
  }
}

// ---------------------------------------------------------------------------
// conv4 (32->1) + epilogue: V_hat = (conv+b4)*sf ; outputs = H + V_hat
// ---------------------------------------------------------------------------
__global__ __launch_bounds__(256) void conv4_k(
    const float* __restrict__ in, const float* __restrict__ w4,
    const float* __restrict__ b4, const float* __restrict__ sfp,
    const float* __restrict__ Hbuf, float* __restrict__ out0,
    float* __restrict__ vhat)
{
  int x = threadIdx.x, y = blockIdx.x;
  int p = y * WIDTH + x;
  float acc = b4[0];
  for (int c = 0; c < 32; c++) {
    const float* ip = in + c * PLANE + p;
    #pragma unroll
    for (int dy = 0; dy < 3; dy++) {
      int yy = y + dy - 1;
      bool rv = (yy >= 0 && yy < 256);
      const float* rp = ip + (dy - 1) * WIDTH;
      float v0 = (rv && x > 0)   ? rp[-1] : 0.f;
      float v1 = rv              ? rp[0]  : 0.f;
      float v2 = (rv && x < 255) ? rp[1]  : 0.f;
      acc = fmaf(w4[c * 9 + dy * 3 + 0], v0, acc);
      acc = fmaf(w4[c * 9 + dy * 3 + 1], v1, acc);
      acc = fmaf(w4[c * 9 + dy * 3 + 2], v2, acc);
    }
  }
  float vh = acc * sfp[0];
  out0[p] = Hbuf[p] + vh;
  vhat[p] = vh;
}

// ---------------------------------------------------------------------------
extern "C" void kernel_launch(void* const* d_in, const int* in_sizes, int n_in,
                              void* d_out, int out_size, void* d_ws, size_t ws_size,
                              hipStream_t stream) {
  const float* inputs = (const float*)d_in[0];
  const float* H0     = (const float*)d_in[1];
  const float* C0     = (const float*)d_in[2];
  const float* c2     = (const float*)d_in[3];
  const float* sf     = (const float*)d_in[4];
  const float* w1     = (const float*)d_in[5];
  const float* b1     = (const float*)d_in[6];
  const float* w2     = (const float*)d_in[7];
  const float* b2     = (const float*)d_in[8];
  const float* w3     = (const float*)d_in[9];
  const float* b3     = (const float*)d_in[10];
  const float* w4     = (const float*)d_in[11];
  const float* b4     = (const float*)d_in[12];
  float* out = (float*)d_out;
  float* ws  = (float*)d_ws;

  // ws layout (floats): needs ~35.8 MB
  float* vs  = ws;                 //   524288  Vs = V/sf, all batches
  float* a1  = ws + 524288;        //  2097152  act1: 32ch, one batch
  float* a2  = ws + 2621440;       //  4194304  act2: 64ch, one batch
  float* a3  = ws + 6815744;       //  2097152  act3: 32ch, one batch
  float* w1t = ws + 8912896;       //      288
  float* w2t = ws + 8913184;       //    18432
  float* w3t = ws + 8931616;       //    18432

  prep_k<<<2048, 256, 0, stream>>>(inputs, H0, C0, c2, sf, out, vs);
  wtrans_k<<<146, 256, 0, stream>>>(w1, w2, w3, w1t, w2t, w3t);

  for (int b = 0; b < 8; b++) {
    conv3x3_k<1, 32, 16, true><<<dim3(256, 2), 256, 0, stream>>>(
        vs + b * PLANE, w1t, b1, a1);
    conv3x3_k<32, 64, 16, true><<<dim3(256, 4), 256, 0, stream>>>(
        a1, w2t, b2, a2);
    conv3x3_k<64, 32, 16, true><<<dim3(256, 2), 256, 0, stream>>>(
        a2, w3t, b3, a3);
    conv4_k<<<256, 256, 0, stream>>>(
        a3, w4, b4, sf,
        out + 524288 + b * PLANE,    // H
        out + b * PLANE,             // outputs
        out + 2621440 + b * PLANE);  // V_hat
  }
}

// Round 2
// 488.215 us; speedup vs baseline: 1.8959x; 1.8959x over previous
//
#include <hip/hip_runtime.h>

#define PLANE 65536
#define WIDTH 256

// ---------------------------------------------------------------------------
// prep: V, C_new, H (Laplacian), and stage Vs = V/sf for the conv chain.
// ---------------------------------------------------------------------------
__global__ __launch_bounds__(256) void prep_k(
    const float* __restrict__ inputs, const float* __restrict__ H0,
    const float* __restrict__ C0, const float* __restrict__ c2p,
    const float* __restrict__ sfp, float* __restrict__ dout,
    float* __restrict__ vs)
{
  int p = blockIdx.x * 256 + threadIdx.x;      // 0 .. 524287
  int b = p >> 16;
  int i = p & 65535;
  int y = i >> 8;
  int x = i & 255;
  float in   = inputs[p];
  float h0   = H0[p];
  float c0a  = C0[b * 131072 + i];             // C0[:,0]
  float up    = (y > 0)   ? inputs[p - 256] : 0.f;
  float down  = (y < 255) ? inputs[p + 256] : 0.f;
  float left  = (x > 0)   ? inputs[p - 1]   : 0.f;
  float right = (x < 255) ? inputs[p + 1]   : 0.f;
  float lap = up + down + left + right - 4.f * in;
  float c2 = c2p[0];
  float sf = sfp[0];
  float Hv = 2.f * in - c0a + c2 * lap;
  float V  = in - h0;
  dout[524288 + p]  = Hv;                      // H
  dout[2097152 + p] = V;                       // V
  dout[1048576 + b * 131072 + i]         = in;   // C_new[:,0]
  dout[1048576 + b * 131072 + 65536 + i] = c0a;  // C_new[:,1]
  vs[p] = V / sf;                              // conv-chain input
}

// ---------------------------------------------------------------------------
// weight transpose: w[cout][cin][3][3] -> wT[(cin*9+tap)][cout]
// ---------------------------------------------------------------------------
__global__ __launch_bounds__(256) void wtrans_k(
    const float* __restrict__ w1, const float* __restrict__ w2,
    const float* __restrict__ w3, float* __restrict__ w1t,
    float* __restrict__ w2t, float* __restrict__ w3t)
{
  int t = blockIdx.x * 256 + threadIdx.x;
  if (t < 288) {                       // w1: [32][1][9] -> [tap][32]
    int tap = t >> 5, cout = t & 31;
    w1t[t] = w1[cout * 9 + tap];
  }
  int t2 = t - 288;
  if (t2 >= 0 && t2 < 18432) {         // w2: [64][32][9] -> [(cin*9+tap)][64]
    int cout = t2 & 63, r = t2 >> 6;
    int cin = r / 9, tap = r % 9;
    w2t[t2] = w2[(cout * 32 + cin) * 9 + tap];
  }
  int t3 = t - (288 + 18432);
  if (t3 >= 0 && t3 < 18432) {         // w3: [32][64][9] -> [(cin*9+tap)][32]
    int cout = t3 & 31, r = t3 >> 5;
    int cin = r / 9, tap = r % 9;
    w3t[t3] = w3[(cout * 64 + cin) * 9 + tap];
  }
}

// ---------------------------------------------------------------------------
// 3x3 SAME conv, batched: in [NB][CIN][256][256] -> out [NB][COUT][256][256].
// Block = 256 threads = one x-row; each thread computes TWO output rows
// (y0, y0+1) for CPB output channels -> 288 FMA : 12 loads per cin.
// grid = (128 rowpairs, COUT/CPB, nb batches). Weights via uniform s_loads.
// ---------------------------------------------------------------------------
template<int CIN, int COUT, int CPB, bool RELU>
__global__ __launch_bounds__(256) void conv3x3_k(
    const float* __restrict__ in, const float* __restrict__ wT,
    const float* __restrict__ bias, float* __restrict__ out)
{
  const int x  = threadIdx.x;            // 0..255
  const int y0 = blockIdx.x * 2;         // 0,2,..,254
  const int cb = blockIdx.y * CPB;
  const int bz = blockIdx.z;
  in  += (size_t)bz * CIN  * PLANE;
  out += (size_t)bz * COUT * PLANE;

  float acc0[CPB], acc1[CPB];
  #pragma unroll
  for (int i = 0; i < CPB; i++) { acc0[i] = bias[cb + i]; acc1[i] = acc0[i]; }

  const bool rtop = (y0 > 0);            // row y0-1 valid
  const bool rbot = (y0 < 254);          // row y0+2 valid
  const bool lok  = (x > 0);
  const bool rok  = (x < 255);

  for (int c = 0; c < CIN; c++) {
    const float* ip = in + c * PLANE + y0 * WIDTH + x;
    float v[4][3];                        // rows y0-1 .. y0+2, cols x-1..x+1
    #pragma unroll
    for (int r = 0; r < 4; r++) {
      const float* rp = ip + (r - 1) * WIDTH;
      bool rv = (r == 0) ? rtop : (r == 3) ? rbot : true;
      v[r][0] = (rv && lok) ? rp[-1] : 0.f;
      v[r][1] = rv          ? rp[0]  : 0.f;
      v[r][2] = (rv && rok) ? rp[1]  : 0.f;
    }
    #pragma unroll
    for (int t = 0; t < 9; t++) {
      int dy = t / 3, dx = t % 3;
      const float* wp = wT + (c * 9 + t) * COUT + cb;   // uniform address
      float va = v[dy][dx], vb = v[dy + 1][dx];
      #pragma unroll
      for (int i = 0; i < CPB; i++) {
        acc0[i] = fmaf(wp[i], va, acc0[i]);
        acc1[i] = fmaf(wp[i], vb, acc1[i]);
      }
    }
  }
  #pragma unroll
  for (int i = 0; i < CPB; i++) {
    float r0 = RELU ? fmaxf(acc0[i], 0.f) : acc0[i];
    float r1 = RELU ? fmaxf(acc1[i], 0.f) : acc1[i];
    out[(cb + i) * PLANE + y0 * WIDTH + x]         = r0;
    out[(cb + i) * PLANE + (y0 + 1) * WIDTH + x]   = r1;
  }
}

// ---------------------------------------------------------------------------
// conv4 (32->1) + epilogue: V_hat = (conv+b4)*sf ; outputs = H + V_hat
// grid = (256 rows, nb batches); b0 = first batch index of this group.
// ---------------------------------------------------------------------------
__global__ __launch_bounds__(256) void conv4_k(
    const float* __restrict__ in, const float* __restrict__ w4,
    const float* __restrict__ b4, const float* __restrict__ sfp,
    float* __restrict__ dout, int b0)
{
  int x = threadIdx.x, y = blockIdx.x;
  int bz = blockIdx.y;
  int b  = b0 + bz;
  in += (size_t)bz * 32 * PLANE;
  int p = y * WIDTH + x;
  float acc = b4[0];
  for (int c = 0; c < 32; c++) {
    const float* ip = in + c * PLANE + p;
    #pragma unroll
    for (int dy = 0; dy < 3; dy++) {
      int yy = y + dy - 1;
      bool rv = (yy >= 0 && yy < 256);
      const float* rp = ip + (dy - 1) * WIDTH;
      float v0 = (rv && x > 0)   ? rp[-1] : 0.f;
      float v1 = rv              ? rp[0]  : 0.f;
      float v2 = (rv && x < 255) ? rp[1]  : 0.f;
      acc = fmaf(w4[c * 9 + dy * 3 + 0], v0, acc);
      acc = fmaf(w4[c * 9 + dy * 3 + 1], v1, acc);
      acc = fmaf(w4[c * 9 + dy * 3 + 2], v2, acc);
    }
  }
  float vh = acc * sfp[0];
  dout[b * PLANE + p]           = dout[524288 + b * PLANE + p] + vh;  // outputs
  dout[2621440 + b * PLANE + p] = vh;                                 // V_hat
}

// ---------------------------------------------------------------------------
extern "C" void kernel_launch(void* const* d_in, const int* in_sizes, int n_in,
                              void* d_out, int out_size, void* d_ws, size_t ws_size,
                              hipStream_t stream) {
  const float* inputs = (const float*)d_in[0];
  const float* H0     = (const float*)d_in[1];
  const float* C0     = (const float*)d_in[2];
  const float* c2     = (const float*)d_in[3];
  const float* sf     = (const float*)d_in[4];
  const float* w1     = (const float*)d_in[5];
  const float* b1     = (const float*)d_in[6];
  const float* w2     = (const float*)d_in[7];
  const float* b2     = (const float*)d_in[8];
  const float* w3     = (const float*)d_in[9];
  const float* b3     = (const float*)d_in[10];
  const float* w4     = (const float*)d_in[11];
  const float* b4     = (const float*)d_in[12];
  float* out = (float*)d_out;
  float* ws  = (float*)d_ws;

  // ws layout (floats):
  //   vs       [524288]          conv input, all 8 batches
  //   w1t/w2t/w3t [37152]        transposed weights
  //   regionA  [nb*32*PLANE]     a1, then reused as a3 (a1 dead after conv2)
  //   regionB  [nb*64*PLANE]     a2
  float* vs  = ws;
  float* w1t = ws + 524288;
  float* w2t = w1t + 288;
  float* w3t = w2t + 18432;
  float* regA = w3t + 18432;     // ws + 561440

  // choose largest batch-group nb that fits the workspace (deterministic)
  int nb = 1;
  for (int cand : {8, 4, 2}) {
    size_t need = (561440 + (size_t)cand * 6291456) * 4;
    if (ws_size >= need) { nb = cand; break; }
  }
  float* regB = regA + (size_t)nb * 2097152;

  prep_k<<<2048, 256, 0, stream>>>(inputs, H0, C0, c2, sf, out, vs);
  wtrans_k<<<146, 256, 0, stream>>>(w1, w2, w3, w1t, w2t, w3t);

  for (int b0 = 0; b0 < 8; b0 += nb) {
    // conv1: vs is 1 channel/image, contiguous -> batch stride == CIN*PLANE
    conv3x3_k<1, 32, 16, true><<<dim3(128, 2, nb), 256, 0, stream>>>(
        vs + (size_t)b0 * PLANE, w1t, b1, regA);
    conv3x3_k<32, 64, 16, true><<<dim3(128, 4, nb), 256, 0, stream>>>(
        regA, w2t, b2, regB);
    conv3x3_k<64, 32, 16, true><<<dim3(128, 2, nb), 256, 0, stream>>>(
        regB, w3t, b3, regA);                 // a3 overwrites a1 (dead)
    conv4_k<<<dim3(256, nb), 256, 0, stream>>>(
        regA, w4, b4, sf, out, b0);
  }
}

// Round 3
// 291.546 us; speedup vs baseline: 3.1748x; 1.6746x over previous
//
#include <hip/hip_runtime.h>
#include <string.h>

#define PLANE 65536
#define WIDTH 256
#define PADW 258
#define PADPLANE 66564   // 258*258

typedef __bf16 v8bf __attribute__((ext_vector_type(8)));
typedef float  v4f  __attribute__((ext_vector_type(4)));

__device__ inline unsigned int pack2(float a, float b) {
  __bf16 ba = (__bf16)a, bb = (__bf16)b;
  unsigned short sa = __builtin_bit_cast(unsigned short, ba);
  unsigned short sb = __builtin_bit_cast(unsigned short, bb);
  return (unsigned int)sa | ((unsigned int)sb << 16);
}

// ---------------------------------------------------------------------------
// prep: V, C_new, H (Laplacian), and stage vs = V/sf (fp32, unpadded NCHW).
// ---------------------------------------------------------------------------
__global__ __launch_bounds__(256) void prep_k(
    const float* __restrict__ inputs, const float* __restrict__ H0,
    const float* __restrict__ C0, const float* __restrict__ c2p,
    const float* __restrict__ sfp, float* __restrict__ dout,
    float* __restrict__ vs)
{
  int p = blockIdx.x * 256 + threadIdx.x;      // 0 .. 524287
  int b = p >> 16;
  int i = p & 65535;
  int y = i >> 8;
  int x = i & 255;
  float in   = inputs[p];
  float h0   = H0[p];
  float c0a  = C0[b * 131072 + i];             // C0[:,0]
  float up    = (y > 0)   ? inputs[p - 256] : 0.f;
  float down  = (y < 255) ? inputs[p + 256] : 0.f;
  float left  = (x > 0)   ? inputs[p - 1]   : 0.f;
  float right = (x < 255) ? inputs[p + 1]   : 0.f;
  float lap = up + down + left + right - 4.f * in;
  float c2 = c2p[0];
  float sf = sfp[0];
  float Hv = 2.f * in - c0a + c2 * lap;
  float V  = in - h0;
  dout[524288 + p]  = Hv;                      // H
  dout[2097152 + p] = V;                       // V
  dout[1048576 + b * 131072 + i]         = in;   // C_new[:,0]
  dout[1048576 + b * 131072 + 65536 + i] = c0a;  // C_new[:,1]
  vs[p] = V / sf;                              // conv-chain input
}

// ---------------------------------------------------------------------------
// weight prep: w1t[tap][cout] fp32; B2t[cout][tap*32+cin] bf16;
//              B3t[cout][tap*64+cin] bf16.
// ---------------------------------------------------------------------------
__global__ __launch_bounds__(256) void wtrans_k(
    const float* __restrict__ w1, const float* __restrict__ w2,
    const float* __restrict__ w3, float* __restrict__ w1t,
    __bf16* __restrict__ B2t, __bf16* __restrict__ B3t)
{
  int t = blockIdx.x * 256 + threadIdx.x;
  if (t < 288) {                       // w1: [32][1][9] -> [tap][32]
    int tap = t >> 5, cout = t & 31;
    w1t[t] = w1[cout * 9 + tap];
  }
  int t2 = t - 288;
  if (t2 >= 0 && t2 < 18432) {         // 64 x 288
    int cout = t2 / 288, k = t2 % 288;
    int tap = k / 32, cin = k % 32;
    B2t[t2] = (__bf16)w2[cout * 288 + cin * 9 + tap];
  }
  int t3 = t - (288 + 18432);
  if (t3 >= 0 && t3 < 18432) {         // 32 x 576
    int cout = t3 / 576, k = t3 % 576;
    int tap = k / 64, cin = k % 64;
    B3t[t3] = (__bf16)w3[cout * 576 + cin * 9 + tap];
  }
}

// ---------------------------------------------------------------------------
// zero the 1-px padding ring of act1/act2/act3 (ws is poisoned every call).
// uint-granular writes; ring = 1028 px per image.
// ---------------------------------------------------------------------------
#define R1 (8 * 1028 * 16)
#define R2 (8 * 1028 * 32)
#define R3 (8 * 1028 * 16)
__global__ __launch_bounds__(256) void zero_k(
    __bf16* __restrict__ a1, __bf16* __restrict__ a2, __bf16* __restrict__ a3)
{
  int t = blockIdx.x * 256 + threadIdx.x;
  unsigned int* p; int C2, idx;
  if (t < R1)            { p = (unsigned int*)a1; C2 = 16; idx = t; }
  else if (t < R1 + R2)  { p = (unsigned int*)a2; C2 = 32; idx = t - R1; }
  else if (t < R1+R2+R3) { p = (unsigned int*)a3; C2 = 16; idx = t - R1 - R2; }
  else return;
  int ch = idx % C2;
  int pr = idx / C2;                 // 0 .. 8*1028-1
  int b = pr / 1028, r = pr % 1028;
  int y, x;
  if      (r < 258) { y = 0;           x = r; }
  else if (r < 516) { y = 257;         x = r - 258; }
  else if (r < 772) { y = r - 516 + 1; x = 0; }
  else              { y = r - 772 + 1; x = 257; }
  p[((size_t)b * PADPLANE + y * PADW + x) * C2 + ch] = 0;
}

// ---------------------------------------------------------------------------
// conv1: 1->32 fp32 vector, thread/pixel; writes act1 NHWC bf16 padded
// (contiguous 64 B per pixel).
// ---------------------------------------------------------------------------
__global__ __launch_bounds__(256) void conv1_k(
    const float* __restrict__ vs, const float* __restrict__ w1t,
    const float* __restrict__ b1, __bf16* __restrict__ act1)
{
  int x = threadIdx.x, y = blockIdx.x, b = blockIdx.y;
  const float* ip = vs + ((size_t)b << 16) + y * WIDTH + x;
  float acc[32];
  #pragma unroll
  for (int i = 0; i < 32; i++) acc[i] = b1[i];
  #pragma unroll
  for (int tap = 0; tap < 9; tap++) {
    int dy = tap / 3 - 1, dx = tap % 3 - 1;
    int yy = y + dy, xx = x + dx;
    bool ok = (yy >= 0 && yy < 256 && xx >= 0 && xx < 256);
    float v = ok ? ip[dy * WIDTH + dx] : 0.f;
    const float* wp = w1t + tap * 32;           // uniform
    #pragma unroll
    for (int i = 0; i < 32; i++) acc[i] = fmaf(wp[i], v, acc[i]);
  }
  unsigned int u[16];
  #pragma unroll
  for (int j = 0; j < 16; j++)
    u[j] = pack2(fmaxf(acc[2*j], 0.f), fmaxf(acc[2*j+1], 0.f));
  size_t pa = ((size_t)b * PADPLANE + (y+1) * PADW + (x+1)) * 32;
  uint4* op = reinterpret_cast<uint4*>(act1 + pa);
  #pragma unroll
  for (int j = 0; j < 4; j++)
    op[j] = make_uint4(u[4*j], u[4*j+1], u[4*j+2], u[4*j+3]);
}

// ---------------------------------------------------------------------------
// MFMA implicit-GEMM 3x3 conv: in NHWC bf16 padded -> out NHWC bf16 padded.
// K = tap*CIN+cin. Block = 1 image row, 4 waves; wave tile M64 x N(COUT).
// A-frag: lane l -> pixel m=base+(l&15), ch (l>>4)*8 (16 B contiguous).
// B-frag: Bt[n=l&15][k-chunk] (16 B contiguous).
// D: row m=(l>>4)*4+r, col n=l&15 (m89-verified layout).
// ---------------------------------------------------------------------------
template<int CIN, int COUT>
__global__ __launch_bounds__(256) void conv_mfma_k(
    const __bf16* __restrict__ in, const __bf16* __restrict__ Bt,
    const float* __restrict__ bias, __bf16* __restrict__ out)
{
  constexpr int NT = COUT / 16;
  constexpr int K9 = 9 * CIN;
  const int lane = threadIdx.x & 63;
  const int wave = threadIdx.x >> 6;
  const int y = blockIdx.x, b = blockIdx.y;
  const int l15 = lane & 15, q = lane >> 4;

  const size_t img = (size_t)b * PADPLANE;
  const int px0 = (y + 1) * PADW + 1 + wave * 64 + l15;
  size_t baseA[4];
  #pragma unroll
  for (int mt = 0; mt < 4; mt++) baseA[mt] = (img + px0 + mt * 16) * CIN + q * 8;
  size_t baseB[NT];
  #pragma unroll
  for (int nt = 0; nt < NT; nt++) baseB[nt] = (size_t)(nt * 16 + l15) * K9 + q * 8;

  v4f acc[4][NT];
  #pragma unroll
  for (int nt = 0; nt < NT; nt++) {
    float bv = bias[nt * 16 + l15];
    #pragma unroll
    for (int mt = 0; mt < 4; mt++) acc[mt][nt] = (v4f){bv, bv, bv, bv};
  }

  #pragma unroll
  for (int tap = 0; tap < 9; tap++) {
    const int dy = tap / 3 - 1, dx = tap % 3 - 1;
    const int offA = (dy * PADW + dx) * CIN;
    #pragma unroll
    for (int kb = 0; kb < CIN / 32; kb++) {
      v8bf af[4], bfr[NT];
      #pragma unroll
      for (int mt = 0; mt < 4; mt++)
        af[mt] = *(const v8bf*)(in + baseA[mt] + offA + kb * 32);
      #pragma unroll
      for (int nt = 0; nt < NT; nt++)
        bfr[nt] = *(const v8bf*)(Bt + baseB[nt] + tap * CIN + kb * 32);
      #pragma unroll
      for (int mt = 0; mt < 4; mt++)
        #pragma unroll
        for (int nt = 0; nt < NT; nt++)
          acc[mt][nt] = __builtin_amdgcn_mfma_f32_16x16x32_bf16(
              af[mt], bfr[nt], acc[mt][nt], 0, 0, 0);
    }
  }

  const int pxs = (y + 1) * PADW + 1 + wave * 64 + q * 4;
  #pragma unroll
  for (int mt = 0; mt < 4; mt++) {
    #pragma unroll
    for (int r = 0; r < 4; r++) {
      size_t pa = (img + pxs + mt * 16 + r) * COUT;
      #pragma unroll
      for (int nt = 0; nt < NT; nt++) {
        float v = fmaxf(acc[mt][nt][r], 0.f);
        out[pa + nt * 16 + l15] = (__bf16)v;
      }
    }
  }
}

// ---------------------------------------------------------------------------
// conv4: 32->1 fp32 vector from act3 (NHWC bf16 padded -> no bounds checks),
// fused epilogue: V_hat = (conv+b4)*sf ; outputs = H + V_hat.
// ---------------------------------------------------------------------------
__global__ __launch_bounds__(256) void conv4_k(
    const __bf16* __restrict__ act3, const float* __restrict__ w4,
    const float* __restrict__ b4, const float* __restrict__ sfp,
    float* __restrict__ dout)
{
  int x = threadIdx.x, y = blockIdx.x, b = blockIdx.y;
  float acc = b4[0];
  const unsigned int* base = (const unsigned int*)(act3 + (size_t)b * PADPLANE * 32);
  #pragma unroll
  for (int tap = 0; tap < 9; tap++) {
    int dy = tap / 3, dx = tap % 3;          // padded coords: rows y..y+2
    const unsigned int* pp = base + ((size_t)(y + dy) * PADW + (x + dx)) * 16;
    #pragma unroll
    for (int j = 0; j < 16; j++) {
      unsigned int u = pp[j];
      float lo = __builtin_bit_cast(float, u << 16);
      float hi = __builtin_bit_cast(float, u & 0xFFFF0000u);
      acc = fmaf(w4[(2*j)     * 9 + tap], lo, acc);
      acc = fmaf(w4[(2*j + 1) * 9 + tap], hi, acc);
    }
  }
  float vh = acc * sfp[0];
  size_t p = ((size_t)b << 16) + y * WIDTH + x;
  dout[p]           = dout[524288 + p] + vh;   // outputs = H + V_hat
  dout[2621440 + p] = vh;                      // V_hat
}

// ---------------------------------------------------------------------------
extern "C" void kernel_launch(void* const* d_in, const int* in_sizes, int n_in,
                              void* d_out, int out_size, void* d_ws, size_t ws_size,
                              hipStream_t stream) {
  const float* inputs = (const float*)d_in[0];
  const float* H0     = (const float*)d_in[1];
  const float* C0     = (const float*)d_in[2];
  const float* c2     = (const float*)d_in[3];
  const float* sf     = (const float*)d_in[4];
  const float* w1     = (const float*)d_in[5];
  const float* b1     = (const float*)d_in[6];
  const float* w2     = (const float*)d_in[7];
  const float* b2     = (const float*)d_in[8];
  const float* w3     = (const float*)d_in[9];
  const float* b3     = (const float*)d_in[10];
  const float* w4     = (const float*)d_in[11];
  const float* b4     = (const float*)d_in[12];
  float* out = (float*)d_out;
  float* ws  = (float*)d_ws;

  // ws layout (floats) — total ~34.6M floats = 138.5 MB:
  float*  vs   = ws;                               // 524288 fp32
  float*  w1t  = ws + 524288;                      // 288 fp32
  __bf16* B2t  = (__bf16*)(ws + 524576);           // 18432 bf16
  __bf16* B3t  = (__bf16*)(ws + 533792);           // 18432 bf16
  __bf16* act1 = (__bf16*)(ws + 543008);           // 8*66564*32 bf16
  __bf16* act2 = act1 + (size_t)8 * PADPLANE * 32; // 8*66564*64 bf16
  __bf16* act3 = act2 + (size_t)8 * PADPLANE * 64; // 8*66564*32 bf16

  prep_k<<<2048, 256, 0, stream>>>(inputs, H0, C0, c2, sf, out, vs);
  wtrans_k<<<146, 256, 0, stream>>>(w1, w2, w3, w1t, B2t, B3t);
  zero_k<<<2056, 256, 0, stream>>>(act1, act2, act3);
  conv1_k<<<dim3(256, 8), 256, 0, stream>>>(vs, w1t, b1, act1);
  conv_mfma_k<32, 64><<<dim3(256, 8), 256, 0, stream>>>(act1, B2t, b2, act2);
  conv_mfma_k<64, 32><<<dim3(256, 8), 256, 0, stream>>>(act2, B3t, b3, act3);
  conv4_k<<<dim3(256, 8), 256, 0, stream>>>(act3, w4, b4, sf, out);
}

// Round 4
// 252.697 us; speedup vs baseline: 3.6629x; 1.1537x over previous
//
#include <hip/hip_runtime.h>

#define PLANE 65536
#define WIDTH 256
#define PADW 258
#define PADPLANE 66564   // 258*258

typedef __bf16 v8bf __attribute__((ext_vector_type(8)));
typedef float  v4f  __attribute__((ext_vector_type(4)));

typedef const __attribute__((address_space(1))) unsigned int* gas_ptr;
typedef __attribute__((address_space(3))) unsigned int* las_ptr;

// async global->LDS, 16 B per lane; LDS dest = wave-uniform base + lane*16
__device__ __forceinline__ void gl_lds(const void* g, void* l) {
  __builtin_amdgcn_global_load_lds((gas_ptr)g, (las_ptr)l, 16, 0, 0);
}

__device__ __forceinline__ unsigned int pack2(float a, float b) {
  __bf16 ba = (__bf16)a, bb = (__bf16)b;
  unsigned short sa = __builtin_bit_cast(unsigned short, ba);
  unsigned short sb = __builtin_bit_cast(unsigned short, bb);
  return (unsigned int)sa | ((unsigned int)sb << 16);
}

// ---------------------------------------------------------------------------
// prep: V, C_new, H (Laplacian), and stage vs = V/sf (fp32, unpadded NCHW).
// ---------------------------------------------------------------------------
__global__ __launch_bounds__(256) void prep_k(
    const float* __restrict__ inputs, const float* __restrict__ H0,
    const float* __restrict__ C0, const float* __restrict__ c2p,
    const float* __restrict__ sfp, float* __restrict__ dout,
    float* __restrict__ vs)
{
  int p = blockIdx.x * 256 + threadIdx.x;      // 0 .. 524287
  int b = p >> 16;
  int i = p & 65535;
  int y = i >> 8;
  int x = i & 255;
  float in   = inputs[p];
  float h0   = H0[p];
  float c0a  = C0[b * 131072 + i];             // C0[:,0]
  float up    = (y > 0)   ? inputs[p - 256] : 0.f;
  float down  = (y < 255) ? inputs[p + 256] : 0.f;
  float left  = (x > 0)   ? inputs[p - 1]   : 0.f;
  float right = (x < 255) ? inputs[p + 1]   : 0.f;
  float lap = up + down + left + right - 4.f * in;
  float c2 = c2p[0];
  float sf = sfp[0];
  float Hv = 2.f * in - c0a + c2 * lap;
  float V  = in - h0;
  dout[524288 + p]  = Hv;                      // H
  dout[2097152 + p] = V;                       // V
  dout[1048576 + b * 131072 + i]         = in;   // C_new[:,0]
  dout[1048576 + b * 131072 + 65536 + i] = c0a;  // C_new[:,1]
  vs[p] = V / sf;                              // conv-chain input
}

// ---------------------------------------------------------------------------
// weight prep: w1t[tap][cout] fp32; B2t[cout][tap*32+cin] bf16;
//              B3t[cout][tap*64+cin] bf16.
// ---------------------------------------------------------------------------
__global__ __launch_bounds__(256) void wtrans_k(
    const float* __restrict__ w1, const float* __restrict__ w2,
    const float* __restrict__ w3, float* __restrict__ w1t,
    __bf16* __restrict__ B2t, __bf16* __restrict__ B3t)
{
  int t = blockIdx.x * 256 + threadIdx.x;
  if (t < 288) {                       // w1: [32][1][9] -> [tap][32]
    int tap = t >> 5, cout = t & 31;
    w1t[t] = w1[cout * 9 + tap];
  }
  int t2 = t - 288;
  if (t2 >= 0 && t2 < 18432) {         // 64 x 288
    int cout = t2 / 288, k = t2 % 288;
    int tap = k / 32, cin = k % 32;
    B2t[t2] = (__bf16)w2[cout * 288 + cin * 9 + tap];
  }
  int t3 = t - (288 + 18432);
  if (t3 >= 0 && t3 < 18432) {         // 32 x 576
    int cout = t3 / 576, k = t3 % 576;
    int tap = k / 64, cin = k % 64;
    B3t[t3] = (__bf16)w3[cout * 576 + cin * 9 + tap];
  }
}

// ---------------------------------------------------------------------------
// zero the 1-px padding ring of act1/act2/act3 (ws is poisoned every call).
// ---------------------------------------------------------------------------
#define R1 (8 * 1028 * 16)
#define R2 (8 * 1028 * 32)
#define R3 (8 * 1028 * 16)
__global__ __launch_bounds__(256) void zero_k(
    __bf16* __restrict__ a1, __bf16* __restrict__ a2, __bf16* __restrict__ a3)
{
  int t = blockIdx.x * 256 + threadIdx.x;
  unsigned int* p; int C2, idx;
  if (t < R1)            { p = (unsigned int*)a1; C2 = 16; idx = t; }
  else if (t < R1 + R2)  { p = (unsigned int*)a2; C2 = 32; idx = t - R1; }
  else if (t < R1+R2+R3) { p = (unsigned int*)a3; C2 = 16; idx = t - R1 - R2; }
  else return;
  int ch = idx % C2;
  int pr = idx / C2;                 // 0 .. 8*1028-1
  int b = pr / 1028, r = pr % 1028;
  int y, x;
  if      (r < 258) { y = 0;           x = r; }
  else if (r < 516) { y = 257;         x = r - 258; }
  else if (r < 772) { y = r - 516 + 1; x = 0; }
  else              { y = r - 772 + 1; x = 257; }
  p[((size_t)b * PADPLANE + y * PADW + x) * C2 + ch] = 0;
}

// ---------------------------------------------------------------------------
// conv1: 1->32 fp32 vector, thread/pixel; writes act1 NHWC bf16 padded.
// ---------------------------------------------------------------------------
__global__ __launch_bounds__(256) void conv1_k(
    const float* __restrict__ vs, const float* __restrict__ w1t,
    const float* __restrict__ b1, __bf16* __restrict__ act1)
{
  int x = threadIdx.x, y = blockIdx.x, b = blockIdx.y;
  const float* ip = vs + ((size_t)b << 16) + y * WIDTH + x;
  float acc[32];
  #pragma unroll
  for (int i = 0; i < 32; i++) acc[i] = b1[i];
  #pragma unroll
  for (int tap = 0; tap < 9; tap++) {
    int dy = tap / 3 - 1, dx = tap % 3 - 1;
    int yy = y + dy, xx = x + dx;
    bool ok = (yy >= 0 && yy < 256 && xx >= 0 && xx < 256);
    float v = ok ? ip[dy * WIDTH + dx] : 0.f;
    const float* wp = w1t + tap * 32;           // uniform
    #pragma unroll
    for (int i = 0; i < 32; i++) acc[i] = fmaf(wp[i], v, acc[i]);
  }
  unsigned int u[16];
  #pragma unroll
  for (int j = 0; j < 16; j++)
    u[j] = pack2(fmaxf(acc[2*j], 0.f), fmaxf(acc[2*j+1], 0.f));
  size_t pa = ((size_t)b * PADPLANE + (y+1) * PADW + (x+1)) * 32;
  uint4* op = reinterpret_cast<uint4*>(act1 + pa);
  #pragma unroll
  for (int j = 0; j < 4; j++)
    op[j] = make_uint4(u[4*j], u[4*j+1], u[4*j+2], u[4*j+3]);
}

// ---------------------------------------------------------------------------
// conv2 (32->64): LDS-staged implicit GEMM. Block = 4 waves = one 256-px row.
// Ring of 3 full padded rows (258 px x 32 ch bf16 = 16512 B each) in LDS.
// Wave tile M64 x N64 (NT=4): per K-chunk 16 MFMA : 4 ds_read_b128.
// ---------------------------------------------------------------------------
#define C2ROW 16512
__device__ __forceinline__ void stage_c2(const __bf16* grow, char* lrow,
                                         int wave, int lane) {
  const char* g = (const char*)grow;
  int base = wave * 258;                        // 258 16B-chunks per wave
  #pragma unroll
  for (int j = 0; j < 4; j++)
    gl_lds(g + (size_t)(base + j*64 + lane)*16, lrow + (base + j*64)*16);
  if (lane < 2)
    gl_lds(g + (size_t)(base + 256 + lane)*16, lrow + (base + 256)*16);
}

template<int ROWS>
__global__ __launch_bounds__(256) void conv2_lds_k(
    const __bf16* __restrict__ act1, const __bf16* __restrict__ Bt,
    const float* __restrict__ bias, __bf16* __restrict__ act2)
{
  const int lane = threadIdx.x & 63, wave = threadIdx.x >> 6;
  const int l15 = lane & 15, q = lane >> 4;
  const int y0 = blockIdx.x * ROWS, b = blockIdx.y;
  __shared__ __align__(16) char smem[3 * C2ROW];
  const __bf16* plane = act1 + (size_t)b * PADPLANE * 32;

  #pragma unroll
  for (int r = 0; r < 3; r++)
    stage_c2(plane + (size_t)(y0 + r) * PADW * 32, smem + r * C2ROW, wave, lane);
  __syncthreads();

  for (int i = 0; i < ROWS; i++) {
    v4f acc[4][4];
    #pragma unroll
    for (int nt = 0; nt < 4; nt++) {
      float bv = bias[nt * 16 + l15];
      #pragma unroll
      for (int mt = 0; mt < 4; mt++) acc[mt][nt] = (v4f){bv, bv, bv, bv};
    }
    #pragma unroll
    for (int tap = 0; tap < 9; tap++) {
      const int dy = tap / 3, dx = tap % 3;
      const char* srow = smem + ((i + dy) % 3) * C2ROW;
      v8bf af[4], bfr[4];
      #pragma unroll
      for (int mt = 0; mt < 4; mt++) {
        int p = wave * 64 + mt * 16 + l15 + dx;           // 0..257
        af[mt] = *(const v8bf*)(srow + p * 64 + q * 16);
      }
      #pragma unroll
      for (int nt = 0; nt < 4; nt++)
        bfr[nt] = *(const v8bf*)(Bt + (size_t)(nt*16 + l15)*288 + tap*32 + q*8);
      #pragma unroll
      for (int mt = 0; mt < 4; mt++)
        #pragma unroll
        for (int nt = 0; nt < 4; nt++)
          acc[mt][nt] = __builtin_amdgcn_mfma_f32_16x16x32_bf16(
              af[mt], bfr[nt], acc[mt][nt], 0, 0, 0);
    }
    // store output row y0+i (padded row y0+i+1), NHWC 64ch
    {
      size_t rb = ((size_t)b * PADPLANE + (size_t)(y0 + i + 1) * PADW + 1) * 64;
      #pragma unroll
      for (int mt = 0; mt < 4; mt++) {
        #pragma unroll
        for (int r = 0; r < 4; r++) {
          size_t pa = rb + (size_t)(wave*64 + mt*16 + q*4 + r) * 64;
          #pragma unroll
          for (int nt = 0; nt < 4; nt++)
            act2[pa + nt*16 + l15] = (__bf16)fmaxf(acc[mt][nt][r], 0.f);
        }
      }
    }
    __syncthreads();                               // readers done with slot i%3
    if (i + 3 < ROWS + 2)
      stage_c2(plane + (size_t)(y0 + i + 3) * PADW * 32,
               smem + (i % 3) * C2ROW, wave, lane);
    __syncthreads();                               // staged row visible
  }
}

// ---------------------------------------------------------------------------
// conv3 (64->32): LDS-staged, x-tiled (128-px tile, 130-px window).
// Block = 2 waves; wave tile M64 x N32. CIN=64 => lane stride 128 B would hit
// banks 0-15 only, so the GLOBAL source address is XOR-swizzled per lane at
// staging time (LDS dest must stay lane-contiguous for global_load_lds);
// fragment reads apply the same XOR -> conflict-free.
// ---------------------------------------------------------------------------
#define C3ROW 16640   // 130 px * 64 ch * 2 B
__device__ __forceinline__ int swz8(int c) {
  return (c & ~7) | ((c & 7) ^ ((c >> 3) & 7));
}
__device__ __forceinline__ void stage_c3(const __bf16* grow, char* lrow,
                                         int wave, int lane) {
  const char* g = (const char*)grow;
  int base = wave * 520;                        // 520 chunks per wave (2 waves)
  #pragma unroll
  for (int j = 0; j < 8; j++) {
    int c = base + j*64 + lane;
    gl_lds(g + (size_t)swz8(c)*16, lrow + (base + j*64)*16);
  }
  if (lane < 8) {
    int c = base + 512 + lane;
    gl_lds(g + (size_t)swz8(c)*16, lrow + (base + 512)*16);
  }
}

template<int ROWS>
__global__ __launch_bounds__(128) void conv3_lds_k(
    const __bf16* __restrict__ act2, const __bf16* __restrict__ Bt,
    const float* __restrict__ bias, __bf16* __restrict__ act3)
{
  const int lane = threadIdx.x & 63, wave = threadIdx.x >> 6;
  const int l15 = lane & 15, q = lane >> 4;
  const int y0 = blockIdx.x * ROWS, xt = blockIdx.y, b = blockIdx.z;
  __shared__ __align__(16) char smem[3 * C3ROW];
  const __bf16* plane = act2 + (size_t)b * PADPLANE * 64;

  #pragma unroll
  for (int r = 0; r < 3; r++)
    stage_c3(plane + ((size_t)(y0 + r) * PADW + xt * 128) * 64,
             smem + r * C3ROW, wave, lane);
  __syncthreads();

  for (int i = 0; i < ROWS; i++) {
    v4f acc[4][2];
    #pragma unroll
    for (int nt = 0; nt < 2; nt++) {
      float bv = bias[nt * 16 + l15];
      #pragma unroll
      for (int mt = 0; mt < 4; mt++) acc[mt][nt] = (v4f){bv, bv, bv, bv};
    }
    #pragma unroll
    for (int tap = 0; tap < 9; tap++) {
      const int dy = tap / 3, dx = tap % 3;
      const char* srow = smem + ((i + dy) % 3) * C3ROW;
      #pragma unroll
      for (int kb = 0; kb < 2; kb++) {
        v8bf af[4], bfr[2];
        #pragma unroll
        for (int mt = 0; mt < 4; mt++) {
          int p = wave * 64 + mt * 16 + l15 + dx;         // 0..129
          int j = kb * 4 + q;
          af[mt] = *(const v8bf*)(srow + (p * 8 + (j ^ (p & 7))) * 16);
        }
        #pragma unroll
        for (int nt = 0; nt < 2; nt++)
          bfr[nt] = *(const v8bf*)(Bt + (size_t)(nt*16 + l15)*576
                                      + tap*64 + kb*32 + q*8);
        #pragma unroll
        for (int mt = 0; mt < 4; mt++)
          #pragma unroll
          for (int nt = 0; nt < 2; nt++)
            acc[mt][nt] = __builtin_amdgcn_mfma_f32_16x16x32_bf16(
                af[mt], bfr[nt], acc[mt][nt], 0, 0, 0);
      }
    }
    {
      size_t rb = ((size_t)b * PADPLANE + (size_t)(y0 + i + 1) * PADW
                   + xt * 128 + 1) * 32;
      #pragma unroll
      for (int mt = 0; mt < 4; mt++) {
        #pragma unroll
        for (int r = 0; r < 4; r++) {
          size_t pa = rb + (size_t)(wave*64 + mt*16 + q*4 + r) * 32;
          #pragma unroll
          for (int nt = 0; nt < 2; nt++)
            act3[pa + nt*16 + l15] = (__bf16)fmaxf(acc[mt][nt][r], 0.f);
        }
      }
    }
    __syncthreads();
    if (i + 3 < ROWS + 2)
      stage_c3(plane + ((size_t)(y0 + i + 3) * PADW + xt * 128) * 64,
               smem + (i % 3) * C3ROW, wave, lane);
    __syncthreads();
  }
}

// ---------------------------------------------------------------------------
// conv4: 32->1 fp32 vector from act3 (NHWC bf16 padded), 2 output rows per
// thread (4 tap-rows instead of 2x3), fused epilogue.
// ---------------------------------------------------------------------------
__global__ __launch_bounds__(256) void conv4_k(
    const __bf16* __restrict__ act3, const float* __restrict__ w4,
    const float* __restrict__ b4, const float* __restrict__ sfp,
    float* __restrict__ dout)
{
  int x = threadIdx.x, y0 = blockIdx.x * 2, b = blockIdx.y;
  float acc0 = b4[0], acc1 = b4[0];
  const unsigned int* base =
      (const unsigned int*)(act3 + (size_t)b * PADPLANE * 32);
  #pragma unroll
  for (int dx = 0; dx < 3; dx++) {
    #pragma unroll
    for (int dyr = 0; dyr < 4; dyr++) {
      const unsigned int* pp = base + ((size_t)(y0 + dyr) * PADW + (x + dx)) * 16;
      #pragma unroll
      for (int j = 0; j < 16; j++) {
        unsigned int u = pp[j];
        float lo = __builtin_bit_cast(float, u << 16);
        float hi = __builtin_bit_cast(float, u & 0xFFFF0000u);
        if (dyr < 3) {
          acc0 = fmaf(w4[(2*j)   * 9 + dyr*3 + dx], lo, acc0);
          acc0 = fmaf(w4[(2*j+1) * 9 + dyr*3 + dx], hi, acc0);
        }
        if (dyr >= 1) {
          acc1 = fmaf(w4[(2*j)   * 9 + (dyr-1)*3 + dx], lo, acc1);
          acc1 = fmaf(w4[(2*j+1) * 9 + (dyr-1)*3 + dx], hi, acc1);
        }
      }
    }
  }
  float sf = sfp[0];
  size_t p0 = ((size_t)b << 16) + (size_t)y0 * WIDTH + x;
  float vh0 = acc0 * sf, vh1 = acc1 * sf;
  dout[p0]                    = dout[524288 + p0] + vh0;
  dout[2621440 + p0]          = vh0;
  dout[p0 + WIDTH]            = dout[524288 + p0 + WIDTH] + vh1;
  dout[2621440 + p0 + WIDTH]  = vh1;
}

// ---------------------------------------------------------------------------
extern "C" void kernel_launch(void* const* d_in, const int* in_sizes, int n_in,
                              void* d_out, int out_size, void* d_ws, size_t ws_size,
                              hipStream_t stream) {
  const float* inputs = (const float*)d_in[0];
  const float* H0     = (const float*)d_in[1];
  const float* C0     = (const float*)d_in[2];
  const float* c2     = (const float*)d_in[3];
  const float* sf     = (const float*)d_in[4];
  const float* w1     = (const float*)d_in[5];
  const float* b1     = (const float*)d_in[6];
  const float* w2     = (const float*)d_in[7];
  const float* b2     = (const float*)d_in[8];
  const float* w3     = (const float*)d_in[9];
  const float* b3     = (const float*)d_in[10];
  const float* w4     = (const float*)d_in[11];
  const float* b4     = (const float*)d_in[12];
  float* out = (float*)d_out;
  float* ws  = (float*)d_ws;

  float*  vs   = ws;                               // 524288 fp32
  float*  w1t  = ws + 524288;                      // 288 fp32
  __bf16* B2t  = (__bf16*)(ws + 524576);           // 18432 bf16
  __bf16* B3t  = (__bf16*)(ws + 533792);           // 18432 bf16
  __bf16* act1 = (__bf16*)(ws + 543008);           // 8*66564*32 bf16
  __bf16* act2 = act1 + (size_t)8 * PADPLANE * 32; // 8*66564*64 bf16
  __bf16* act3 = act2 + (size_t)8 * PADPLANE * 64; // 8*66564*32 bf16

  prep_k<<<2048, 256, 0, stream>>>(inputs, H0, C0, c2, sf, out, vs);
  wtrans_k<<<146, 256, 0, stream>>>(w1, w2, w3, w1t, B2t, B3t);
  zero_k<<<2056, 256, 0, stream>>>(act1, act2, act3);
  conv1_k<<<dim3(256, 8), 256, 0, stream>>>(vs, w1t, b1, act1);
  conv2_lds_k<4><<<dim3(64, 8), 256, 0, stream>>>(act1, B2t, b2, act2);
  conv3_lds_k<4><<<dim3(64, 2, 8), 128, 0, stream>>>(act2, B3t, b3, act3);
  conv4_k<<<dim3(128, 8), 256, 0, stream>>>(act3, w4, b4, sf, out);
}

// Round 6
// 212.092 us; speedup vs baseline: 4.3641x; 1.1914x over previous
//
#include <hip/hip_runtime.h>

#define PLANE 65536
#define WIDTH 256
#define PADW 258
#define PADPLANE 66564   // 258*258

typedef __bf16 v8bf __attribute__((ext_vector_type(8)));
typedef float  v4f  __attribute__((ext_vector_type(4)));

typedef const __attribute__((address_space(1))) unsigned int* gas_ptr;
typedef __attribute__((address_space(3))) unsigned int* las_ptr;

// async global->LDS, 16 B per lane; LDS dest = wave-uniform base + lane*16
__device__ __forceinline__ void gl_lds(const void* g, void* l) {
  __builtin_amdgcn_global_load_lds((gas_ptr)g, (las_ptr)l, 16, 0, 0);
}

__device__ __forceinline__ unsigned int pack2(float a, float b) {
  __bf16 ba = (__bf16)a, bb = (__bf16)b;
  unsigned short sa = __builtin_bit_cast(unsigned short, ba);
  unsigned short sb = __builtin_bit_cast(unsigned short, bb);
  return (unsigned int)sa | ((unsigned int)sb << 16);
}

// ---------------------------------------------------------------------------
// prep: V, C_new, H (Laplacian), and stage vs = V/sf (fp32, unpadded NCHW).
// ---------------------------------------------------------------------------
__global__ __launch_bounds__(256) void prep_k(
    const float* __restrict__ inputs, const float* __restrict__ H0,
    const float* __restrict__ C0, const float* __restrict__ c2p,
    const float* __restrict__ sfp, float* __restrict__ dout,
    float* __restrict__ vs)
{
  int p = blockIdx.x * 256 + threadIdx.x;      // 0 .. 524287
  int b = p >> 16;
  int i = p & 65535;
  int y = i >> 8;
  int x = i & 255;
  float in   = inputs[p];
  float h0   = H0[p];
  float c0a  = C0[b * 131072 + i];             // C0[:,0]
  float up    = (y > 0)   ? inputs[p - 256] : 0.f;
  float down  = (y < 255) ? inputs[p + 256] : 0.f;
  float left  = (x > 0)   ? inputs[p - 1]   : 0.f;
  float right = (x < 255) ? inputs[p + 1]   : 0.f;
  float lap = up + down + left + right - 4.f * in;
  float c2 = c2p[0];
  float sf = sfp[0];
  float Hv = 2.f * in - c0a + c2 * lap;
  float V  = in - h0;
  dout[524288 + p]  = Hv;                      // H
  dout[2097152 + p] = V;                       // V
  dout[1048576 + b * 131072 + i]         = in;   // C_new[:,0]
  dout[1048576 + b * 131072 + 65536 + i] = c0a;  // C_new[:,1]
  vs[p] = V / sf;                              // conv-chain input
}

// ---------------------------------------------------------------------------
// weight prep: w1t[tap][cout] fp32; B2t[cout][tap*32+cin] bf16;
//              B3t[cout][tap*64+cin] bf16; w4t[tap][cin] fp32.
// ---------------------------------------------------------------------------
__global__ __launch_bounds__(256) void wtrans_k(
    const float* __restrict__ w1, const float* __restrict__ w2,
    const float* __restrict__ w3, const float* __restrict__ w4,
    float* __restrict__ w1t, __bf16* __restrict__ B2t,
    __bf16* __restrict__ B3t, float* __restrict__ w4t)
{
  int t = blockIdx.x * 256 + threadIdx.x;
  if (t < 288) {                       // w1: [32][1][9] -> [tap][32]
    int tap = t >> 5, cout = t & 31;
    w1t[t] = w1[cout * 9 + tap];
  }
  int t2 = t - 288;
  if (t2 >= 0 && t2 < 18432) {         // 64 x 288
    int cout = t2 / 288, k = t2 % 288;
    int tap = k / 32, cin = k % 32;
    B2t[t2] = (__bf16)w2[cout * 288 + cin * 9 + tap];
  }
  int t3 = t - (288 + 18432);
  if (t3 >= 0 && t3 < 18432) {         // 32 x 576
    int cout = t3 / 576, k = t3 % 576;
    int tap = k / 64, cin = k % 64;
    B3t[t3] = (__bf16)w3[cout * 576 + cin * 9 + tap];
  }
  int t4 = t - (288 + 18432 + 18432);
  if (t4 >= 0 && t4 < 288) {           // w4: [1][32][9] -> [tap][32]
    int tap = t4 >> 5, cin = t4 & 31;
    w4t[t4] = w4[cin * 9 + tap];
  }
}

// ---------------------------------------------------------------------------
// zero the 1-px padding ring of act1/act2/act3 (ws is poisoned every call).
// ---------------------------------------------------------------------------
#define R1 (8 * 1028 * 16)
#define R2 (8 * 1028 * 32)
#define R3 (8 * 1028 * 16)
__global__ __launch_bounds__(256) void zero_k(
    __bf16* __restrict__ a1, __bf16* __restrict__ a2, __bf16* __restrict__ a3)
{
  int t = blockIdx.x * 256 + threadIdx.x;
  unsigned int* p; int C2, idx;
  if (t < R1)            { p = (unsigned int*)a1; C2 = 16; idx = t; }
  else if (t < R1 + R2)  { p = (unsigned int*)a2; C2 = 32; idx = t - R1; }
  else if (t < R1+R2+R3) { p = (unsigned int*)a3; C2 = 16; idx = t - R1 - R2; }
  else return;
  int ch = idx % C2;
  int pr = idx / C2;                 // 0 .. 8*1028-1
  int b = pr / 1028, r = pr % 1028;
  int y, x;
  if      (r < 258) { y = 0;           x = r; }
  else if (r < 516) { y = 257;         x = r - 258; }
  else if (r < 772) { y = r - 516 + 1; x = 0; }
  else              { y = r - 772 + 1; x = 257; }
  p[((size_t)b * PADPLANE + y * PADW + x) * C2 + ch] = 0;
}

// ---------------------------------------------------------------------------
// conv1: 1->32 fp32 vector, thread/pixel; writes act1 NHWC bf16 padded.
// ---------------------------------------------------------------------------
__global__ __launch_bounds__(256) void conv1_k(
    const float* __restrict__ vs, const float* __restrict__ w1t,
    const float* __restrict__ b1, __bf16* __restrict__ act1)
{
  int x = threadIdx.x, y = blockIdx.x, b = blockIdx.y;
  const float* ip = vs + ((size_t)b << 16) + y * WIDTH + x;
  float acc[32];
  #pragma unroll
  for (int i = 0; i < 32; i++) acc[i] = b1[i];
  #pragma unroll
  for (int tap = 0; tap < 9; tap++) {
    int dy = tap / 3 - 1, dx = tap % 3 - 1;
    int yy = y + dy, xx = x + dx;
    bool ok = (yy >= 0 && yy < 256 && xx >= 0 && xx < 256);
    float v = ok ? ip[dy * WIDTH + dx] : 0.f;
    const float* wp = w1t + tap * 32;           // uniform
    #pragma unroll
    for (int i = 0; i < 32; i++) acc[i] = fmaf(wp[i], v, acc[i]);
  }
  unsigned int u[16];
  #pragma unroll
  for (int j = 0; j < 16; j++)
    u[j] = pack2(fmaxf(acc[2*j], 0.f), fmaxf(acc[2*j+1], 0.f));
  size_t pa = ((size_t)b * PADPLANE + (y+1) * PADW + (x+1)) * 32;
  uint4* op = reinterpret_cast<uint4*>(act1 + pa);
  #pragma unroll
  for (int j = 0; j < 4; j++)
    op[j] = make_uint4(u[4*j], u[4*j+1], u[4*j+2], u[4*j+3]);
}

// ---------------------------------------------------------------------------
// conv2 (32->64): LDS-staged implicit GEMM. Block = 4 waves = one 256-px row.
// Ring of 3 full padded rows (258 px x 32 ch bf16 = 16512 B each) in LDS.
// Wave tile M64 x N64 (NT=4): per K-chunk 16 MFMA : 4 ds_read_b128.
// ---------------------------------------------------------------------------
#define C2ROW 16512
__device__ __forceinline__ void stage_c2(const __bf16* grow, char* lrow,
                                         int wave, int lane) {
  const char* g = (const char*)grow;
  int base = wave * 258;                        // 258 16B-chunks per wave
  #pragma unroll
  for (int j = 0; j < 4; j++)
    gl_lds(g + (size_t)(base + j*64 + lane)*16, lrow + (base + j*64)*16);
  if (lane < 2)
    gl_lds(g + (size_t)(base + 256 + lane)*16, lrow + (base + 256)*16);
}

template<int ROWS>
__global__ __launch_bounds__(256) void conv2_lds_k(
    const __bf16* __restrict__ act1, const __bf16* __restrict__ Bt,
    const float* __restrict__ bias, __bf16* __restrict__ act2)
{
  const int lane = threadIdx.x & 63, wave = threadIdx.x >> 6;
  const int l15 = lane & 15, q = lane >> 4;
  const int y0 = blockIdx.x * ROWS, b = blockIdx.y;
  __shared__ __align__(16) char smem[3 * C2ROW];
  const __bf16* plane = act1 + (size_t)b * PADPLANE * 32;

  #pragma unroll
  for (int r = 0; r < 3; r++)
    stage_c2(plane + (size_t)(y0 + r) * PADW * 32, smem + r * C2ROW, wave, lane);
  __syncthreads();

  for (int i = 0; i < ROWS; i++) {
    v4f acc[4][4];
    #pragma unroll
    for (int nt = 0; nt < 4; nt++) {
      float bv = bias[nt * 16 + l15];
      #pragma unroll
      for (int mt = 0; mt < 4; mt++) acc[mt][nt] = (v4f){bv, bv, bv, bv};
    }
    #pragma unroll
    for (int tap = 0; tap < 9; tap++) {
      const int dy = tap / 3, dx = tap % 3;
      const char* srow = smem + ((i + dy) % 3) * C2ROW;
      v8bf af[4], bfr[4];
      #pragma unroll
      for (int mt = 0; mt < 4; mt++) {
        int p = wave * 64 + mt * 16 + l15 + dx;           // 0..257
        af[mt] = *(const v8bf*)(srow + p * 64 + q * 16);
      }
      #pragma unroll
      for (int nt = 0; nt < 4; nt++)
        bfr[nt] = *(const v8bf*)(Bt + (size_t)(nt*16 + l15)*288 + tap*32 + q*8);
      #pragma unroll
      for (int mt = 0; mt < 4; mt++)
        #pragma unroll
        for (int nt = 0; nt < 4; nt++)
          acc[mt][nt] = __builtin_amdgcn_mfma_f32_16x16x32_bf16(
              af[mt], bfr[nt], acc[mt][nt], 0, 0, 0);
    }
    // store output row y0+i (padded row y0+i+1), NHWC 64ch
    {
      size_t rb = ((size_t)b * PADPLANE + (size_t)(y0 + i + 1) * PADW + 1) * 64;
      #pragma unroll
      for (int mt = 0; mt < 4; mt++) {
        #pragma unroll
        for (int r = 0; r < 4; r++) {
          size_t pa = rb + (size_t)(wave*64 + mt*16 + q*4 + r) * 64;
          #pragma unroll
          for (int nt = 0; nt < 4; nt++)
            act2[pa + nt*16 + l15] = (__bf16)fmaxf(acc[mt][nt][r], 0.f);
        }
      }
    }
    __syncthreads();                               // readers done with slot i%3
    if (i + 3 < ROWS + 2)
      stage_c2(plane + (size_t)(y0 + i + 3) * PADW * 32,
               smem + (i % 3) * C2ROW, wave, lane);
    __syncthreads();                               // staged row visible
  }
}

// ---------------------------------------------------------------------------
// conv3 (64->32): LDS-staged, x-tiled (128-px tile, 130-px window).
// Block = 2 waves; wave tile M64 x N32. CIN=64 => lane stride 128 B would hit
// banks 0-15 only, so the GLOBAL source address is XOR-swizzled per lane at
// staging time (LDS dest must stay lane-contiguous for global_load_lds);
// fragment reads apply the same XOR -> conflict-free.
// ---------------------------------------------------------------------------
#define C3ROW 16640   // 130 px * 64 ch * 2 B
__device__ __forceinline__ int swz8(int c) {
  return (c & ~7) | ((c & 7) ^ ((c >> 3) & 7));
}
__device__ __forceinline__ void stage_c3(const __bf16* grow, char* lrow,
                                         int wave, int lane) {
  const char* g = (const char*)grow;
  int base = wave * 520;                        // 520 chunks per wave (2 waves)
  #pragma unroll
  for (int j = 0; j < 8; j++) {
    int c = base + j*64 + lane;
    gl_lds(g + (size_t)swz8(c)*16, lrow + (base + j*64)*16);
  }
  if (lane < 8) {
    int c = base + 512 + lane;
    gl_lds(g + (size_t)swz8(c)*16, lrow + (base + 512)*16);
  }
}

template<int ROWS>
__global__ __launch_bounds__(128) void conv3_lds_k(
    const __bf16* __restrict__ act2, const __bf16* __restrict__ Bt,
    const float* __restrict__ bias, __bf16* __restrict__ act3)
{
  const int lane = threadIdx.x & 63, wave = threadIdx.x >> 6;
  const int l15 = lane & 15, q = lane >> 4;
  const int y0 = blockIdx.x * ROWS, xt = blockIdx.y, b = blockIdx.z;
  __shared__ __align__(16) char smem[3 * C3ROW];
  const __bf16* plane = act2 + (size_t)b * PADPLANE * 64;

  #pragma unroll
  for (int r = 0; r < 3; r++)
    stage_c3(plane + ((size_t)(y0 + r) * PADW + xt * 128) * 64,
             smem + r * C3ROW, wave, lane);
  __syncthreads();

  for (int i = 0; i < ROWS; i++) {
    v4f acc[4][2];
    #pragma unroll
    for (int nt = 0; nt < 2; nt++) {
      float bv = bias[nt * 16 + l15];
      #pragma unroll
      for (int mt = 0; mt < 4; mt++) acc[mt][nt] = (v4f){bv, bv, bv, bv};
    }
    #pragma unroll
    for (int tap = 0; tap < 9; tap++) {
      const int dy = tap / 3, dx = tap % 3;
      const char* srow = smem + ((i + dy) % 3) * C3ROW;
      #pragma unroll
      for (int kb = 0; kb < 2; kb++) {
        v8bf af[4], bfr[2];
        #pragma unroll
        for (int mt = 0; mt < 4; mt++) {
          int p = wave * 64 + mt * 16 + l15 + dx;         // 0..129
          int j = kb * 4 + q;
          af[mt] = *(const v8bf*)(srow + (p * 8 + (j ^ (p & 7))) * 16);
        }
        #pragma unroll
        for (int nt = 0; nt < 2; nt++)
          bfr[nt] = *(const v8bf*)(Bt + (size_t)(nt*16 + l15)*576
                                      + tap*64 + kb*32 + q*8);
        #pragma unroll
        for (int mt = 0; mt < 4; mt++)
          #pragma unroll
          for (int nt = 0; nt < 2; nt++)
            acc[mt][nt] = __builtin_amdgcn_mfma_f32_16x16x32_bf16(
                af[mt], bfr[nt], acc[mt][nt], 0, 0, 0);
      }
    }
    {
      size_t rb = ((size_t)b * PADPLANE + (size_t)(y0 + i + 1) * PADW
                   + xt * 128 + 1) * 32;
      #pragma unroll
      for (int mt = 0; mt < 4; mt++) {
        #pragma unroll
        for (int r = 0; r < 4; r++) {
          size_t pa = rb + (size_t)(wave*64 + mt*16 + q*4 + r) * 32;
          #pragma unroll
          for (int nt = 0; nt < 2; nt++)
            act3[pa + nt*16 + l15] = (__bf16)fmaxf(acc[mt][nt][r], 0.f);
        }
      }
    }
    __syncthreads();
    if (i + 3 < ROWS + 2)
      stage_c3(plane + ((size_t)(y0 + i + 3) * PADW + xt * 128) * 64,
               smem + (i % 3) * C3ROW, wave, lane);
    __syncthreads();
  }
}

// ---------------------------------------------------------------------------
// conv4 (32->1) row-streaming: thread = one x-column, block = 4 output rows.
// Each padded row is loaded ONCE (12x uint4 = 3 px x 32 ch contiguous NHWC)
// and contributes to up to 3 rotating accumulators (tap-rows 2/1/0).
// GUARD: only rows this block owns (0 <= t-dyp < C4ROWS) — contributions
// with dyp > t belong to the previous block (round-5 contamination bug).
// Fused epilogue: V_hat = (conv+b4)*sf ; outputs = H + V_hat.
// ---------------------------------------------------------------------------
#define C4ROWS 4
__global__ __launch_bounds__(256) void conv4_k(
    const __bf16* __restrict__ act3, const float* __restrict__ w4t,
    const float* __restrict__ b4, const float* __restrict__ sfp,
    float* __restrict__ dout)
{
  const int x = threadIdx.x, y0 = blockIdx.x * C4ROWS, b = blockIdx.y;
  const float b4v = b4[0], sf = sfp[0];
  const uint4* base = (const uint4*)(act3 + (size_t)b * PADPLANE * 32);
  float accs[3] = {b4v, b4v, b4v};

  #pragma unroll
  for (int t = 0; t < C4ROWS + 2; t++) {
    const int pr = y0 + t;                       // padded row index
    const uint4* rp = base + ((size_t)pr * PADW + x) * 4;   // 4 uint4 / px
    uint4 L[12];
    #pragma unroll
    for (int j = 0; j < 12; j++) L[j] = rp[j];
    #pragma unroll
    for (int j = 0; j < 12; j++) {
      const int dx = j >> 2, c0 = (j & 3) * 8;
      unsigned int uu[4] = {L[j].x, L[j].y, L[j].z, L[j].w};
      float f[8];
      #pragma unroll
      for (int k = 0; k < 4; k++) {
        f[2*k]   = __builtin_bit_cast(float, uu[k] << 16);
        f[2*k+1] = __builtin_bit_cast(float, uu[k] & 0xFFFF0000u);
      }
      // padded row pr serves output row r = pr - dyp with tap-row dyp;
      // only accumulate rows owned by this block (static pruning).
      #pragma unroll
      for (int dyp = 0; dyp < 3; dyp++) {
        if (dyp <= t && t - dyp < C4ROWS) {
          const int slot = (t - dyp) % 3;
          const float* wp = w4t + (dyp * 3 + dx) * 32 + c0;   // uniform
          #pragma unroll
          for (int k = 0; k < 8; k++)
            accs[slot] = fmaf(wp[k], f[k], accs[slot]);
        }
      }
    }
    if (t >= 2) {                                // output row y0+t-2 complete
      const int r = y0 + t - 2, slot = (t - 2) % 3;
      size_t p0 = ((size_t)b << 16) + (size_t)r * WIDTH + x;
      float vh = accs[slot] * sf;
      dout[p0]           = dout[524288 + p0] + vh;   // outputs = H + V_hat
      dout[2621440 + p0] = vh;                       // V_hat
      accs[slot] = b4v;
    }
  }
}

// ---------------------------------------------------------------------------
extern "C" void kernel_launch(void* const* d_in, const int* in_sizes, int n_in,
                              void* d_out, int out_size, void* d_ws, size_t ws_size,
                              hipStream_t stream) {
  const float* inputs = (const float*)d_in[0];
  const float* H0     = (const float*)d_in[1];
  const float* C0     = (const float*)d_in[2];
  const float* c2     = (const float*)d_in[3];
  const float* sf     = (const float*)d_in[4];
  const float* w1     = (const float*)d_in[5];
  const float* b1     = (const float*)d_in[6];
  const float* w2     = (const float*)d_in[7];
  const float* b2     = (const float*)d_in[8];
  const float* w3     = (const float*)d_in[9];
  const float* b3     = (const float*)d_in[10];
  const float* w4     = (const float*)d_in[11];
  const float* b4     = (const float*)d_in[12];
  float* out = (float*)d_out;
  float* ws  = (float*)d_ws;

  float*  vs   = ws;                               // 524288 fp32
  float*  w1t  = ws + 524288;                      // 288 fp32
  float*  w4t  = ws + 524576;                      // 288 fp32
  __bf16* B2t  = (__bf16*)(ws + 524864);           // 18432 bf16
  __bf16* B3t  = (__bf16*)(ws + 534080);           // 18432 bf16
  __bf16* act1 = (__bf16*)(ws + 543296);           // 8*66564*32 bf16
  __bf16* act2 = act1 + (size_t)8 * PADPLANE * 32; // 8*66564*64 bf16
  __bf16* act3 = act2 + (size_t)8 * PADPLANE * 64; // 8*66564*32 bf16

  prep_k<<<2048, 256, 0, stream>>>(inputs, H0, C0, c2, sf, out, vs);
  wtrans_k<<<147, 256, 0, stream>>>(w1, w2, w3, w4, w1t, B2t, B3t, w4t);
  zero_k<<<2056, 256, 0, stream>>>(act1, act2, act3);
  conv1_k<<<dim3(256, 8), 256, 0, stream>>>(vs, w1t, b1, act1);
  conv2_lds_k<4><<<dim3(64, 8), 256, 0, stream>>>(act1, B2t, b2, act2);
  conv3_lds_k<4><<<dim3(64, 2, 8), 128, 0, stream>>>(act2, B3t, b3, act3);
  conv4_k<<<dim3(64, 8), 256, 0, stream>>>(act3, w4t, b4, sf, out);
}

// Round 7
// 192.136 us; speedup vs baseline: 4.8174x; 1.1039x over previous
//
#include <hip/hip_runtime.h>

#define PLANE 65536
#define WIDTH 256
#define PADW 258
#define PADPLANE 66564   // 258*258

typedef __bf16 v8bf __attribute__((ext_vector_type(8)));
typedef float  v4f  __attribute__((ext_vector_type(4)));

typedef const __attribute__((address_space(1))) unsigned int* gas_ptr;
typedef __attribute__((address_space(3))) unsigned int* las_ptr;

// async global->LDS, 16 B per lane; LDS dest = wave-uniform base + lane*16
__device__ __forceinline__ void gl_lds(const void* g, void* l) {
  __builtin_amdgcn_global_load_lds((gas_ptr)g, (las_ptr)l, 16, 0, 0);
}

// self-inverse 16B-chunk swizzle within 8-chunk groups: breaks power-of-2
// bank strides for both CIN=32 (4 chunks/px) and CIN=64 (8 chunks/px).
__device__ __forceinline__ int swz(int c) {
  return (c & ~7) | ((c & 7) ^ ((c >> 3) & 7));
}

__device__ __forceinline__ unsigned int pack2(float a, float b) {
  __bf16 ba = (__bf16)a, bb = (__bf16)b;
  unsigned short sa = __builtin_bit_cast(unsigned short, ba);
  unsigned short sb = __builtin_bit_cast(unsigned short, bb);
  return (unsigned int)sa | ((unsigned int)sb << 16);
}

// ---------------------------------------------------------------------------
// prep: V, C_new, H (Laplacian), and stage vs = V/sf (fp32, unpadded NCHW).
// ---------------------------------------------------------------------------
__global__ __launch_bounds__(256) void prep_k(
    const float* __restrict__ inputs, const float* __restrict__ H0,
    const float* __restrict__ C0, const float* __restrict__ c2p,
    const float* __restrict__ sfp, float* __restrict__ dout,
    float* __restrict__ vs)
{
  int p = blockIdx.x * 256 + threadIdx.x;      // 0 .. 524287
  int b = p >> 16;
  int i = p & 65535;
  int y = i >> 8;
  int x = i & 255;
  float in   = inputs[p];
  float h0   = H0[p];
  float c0a  = C0[b * 131072 + i];             // C0[:,0]
  float up    = (y > 0)   ? inputs[p - 256] : 0.f;
  float down  = (y < 255) ? inputs[p + 256] : 0.f;
  float left  = (x > 0)   ? inputs[p - 1]   : 0.f;
  float right = (x < 255) ? inputs[p + 1]   : 0.f;
  float lap = up + down + left + right - 4.f * in;
  float c2 = c2p[0];
  float sf = sfp[0];
  float Hv = 2.f * in - c0a + c2 * lap;
  float V  = in - h0;
  dout[524288 + p]  = Hv;                      // H
  dout[2097152 + p] = V;                       // V
  dout[1048576 + b * 131072 + i]         = in;   // C_new[:,0]
  dout[1048576 + b * 131072 + 65536 + i] = c0a;  // C_new[:,1]
  vs[p] = V / sf;                              // conv-chain input
}

// ---------------------------------------------------------------------------
// weight prep: w1t[tap][cout] fp32; B2t[cout][tap*32+cin] bf16;
//              B3t[cout][tap*64+cin] bf16; w4t[tap][cin] fp32.
// ---------------------------------------------------------------------------
__global__ __launch_bounds__(256) void wtrans_k(
    const float* __restrict__ w1, const float* __restrict__ w2,
    const float* __restrict__ w3, const float* __restrict__ w4,
    float* __restrict__ w1t, __bf16* __restrict__ B2t,
    __bf16* __restrict__ B3t, float* __restrict__ w4t)
{
  int t = blockIdx.x * 256 + threadIdx.x;
  if (t < 288) {                       // w1: [32][1][9] -> [tap][32]
    int tap = t >> 5, cout = t & 31;
    w1t[t] = w1[cout * 9 + tap];
  }
  int t2 = t - 288;
  if (t2 >= 0 && t2 < 18432) {         // 64 x 288
    int cout = t2 / 288, k = t2 % 288;
    int tap = k / 32, cin = k % 32;
    B2t[t2] = (__bf16)w2[cout * 288 + cin * 9 + tap];
  }
  int t3 = t - (288 + 18432);
  if (t3 >= 0 && t3 < 18432) {         // 32 x 576
    int cout = t3 / 576, k = t3 % 576;
    int tap = k / 64, cin = k % 64;
    B3t[t3] = (__bf16)w3[cout * 576 + cin * 9 + tap];
  }
  int t4 = t - (288 + 18432 + 18432);
  if (t4 >= 0 && t4 < 288) {           // w4: [1][32][9] -> [tap][32]
    int tap = t4 >> 5, cin = t4 & 31;
    w4t[t4] = w4[cin * 9 + tap];
  }
}

// ---------------------------------------------------------------------------
// zero the 1-px padding ring of act1/act2/act3 (ws is poisoned every call).
// ---------------------------------------------------------------------------
#define R1 (8 * 1028 * 16)
#define R2 (8 * 1028 * 32)
#define R3 (8 * 1028 * 16)
__global__ __launch_bounds__(256) void zero_k(
    __bf16* __restrict__ a1, __bf16* __restrict__ a2, __bf16* __restrict__ a3)
{
  int t = blockIdx.x * 256 + threadIdx.x;
  unsigned int* p; int C2, idx;
  if (t < R1)            { p = (unsigned int*)a1; C2 = 16; idx = t; }
  else if (t < R1 + R2)  { p = (unsigned int*)a2; C2 = 32; idx = t - R1; }
  else if (t < R1+R2+R3) { p = (unsigned int*)a3; C2 = 16; idx = t - R1 - R2; }
  else return;
  int ch = idx % C2;
  int pr = idx / C2;                 // 0 .. 8*1028-1
  int b = pr / 1028, r = pr % 1028;
  int y, x;
  if      (r < 258) { y = 0;           x = r; }
  else if (r < 516) { y = 257;         x = r - 258; }
  else if (r < 772) { y = r - 516 + 1; x = 0; }
  else              { y = r - 772 + 1; x = 257; }
  p[((size_t)b * PADPLANE + y * PADW + x) * C2 + ch] = 0;
}

// ---------------------------------------------------------------------------
// conv1: 1->32 fp32 vector, thread/pixel; writes act1 NHWC bf16 padded.
// ---------------------------------------------------------------------------
__global__ __launch_bounds__(256) void conv1_k(
    const float* __restrict__ vs, const float* __restrict__ w1t,
    const float* __restrict__ b1, __bf16* __restrict__ act1)
{
  int x = threadIdx.x, y = blockIdx.x, b = blockIdx.y;
  const float* ip = vs + ((size_t)b << 16) + y * WIDTH + x;
  float acc[32];
  #pragma unroll
  for (int i = 0; i < 32; i++) acc[i] = b1[i];
  #pragma unroll
  for (int tap = 0; tap < 9; tap++) {
    int dy = tap / 3 - 1, dx = tap % 3 - 1;
    int yy = y + dy, xx = x + dx;
    bool ok = (yy >= 0 && yy < 256 && xx >= 0 && xx < 256);
    float v = ok ? ip[dy * WIDTH + dx] : 0.f;
    const float* wp = w1t + tap * 32;           // uniform
    #pragma unroll
    for (int i = 0; i < 32; i++) acc[i] = fmaf(wp[i], v, acc[i]);
  }
  unsigned int u[16];
  #pragma unroll
  for (int j = 0; j < 16; j++)
    u[j] = pack2(fmaxf(acc[2*j], 0.f), fmaxf(acc[2*j+1], 0.f));
  size_t pa = ((size_t)b * PADPLANE + (y+1) * PADW + (x+1)) * 32;
  uint4* op = reinterpret_cast<uint4*>(act1 + pa);
  #pragma unroll
  for (int j = 0; j < 4; j++)
    op[j] = make_uint4(u[4*j], u[4*j+1], u[4*j+2], u[4*j+3]);
}

// ---------------------------------------------------------------------------
// Unified LDS-staged MFMA 3x3 conv (CIN->COUT), NHWC bf16 padded in/out.
// Block = 256 thr = 4 waves: 2 M-waves (64 px each, x-tile 128, window 130)
//                          x 2 N-waves (COUT/2 couts each, NT = COUT/32).
// B-fragments hoisted to 18 v8bf registers per wave (loop has ZERO global
// loads). Ring of 3 rows in LDS; XOR bank swizzle on the staging SOURCE
// address (LDS dest must stay lane-contiguous for global_load_lds).
// ---------------------------------------------------------------------------
template<int CIN, int COUT, int ROWS>
__global__ __launch_bounds__(256) void conv_lds_k(
    const __bf16* __restrict__ in, const __bf16* __restrict__ Bt,
    const float* __restrict__ bias, __bf16* __restrict__ out)
{
  constexpr int CP    = CIN / 8;        // 16B chunks per pixel (4 or 8)
  constexpr int KB    = CIN / 32;       // K-chunks per tap (1 or 2)
  constexpr int NT    = COUT / 32;      // 16-wide n-tiles per N-wave (2 or 1)
  constexpr int ROWCH = 130 * CP;       // chunks per LDS row (520 / 1040)
  constexpr int ROWB  = ROWCH * 16;     // bytes per LDS row (8320 / 16640)
  constexpr int K9    = 9 * CIN;
  constexpr int PWCH  = ROWCH / 4;      // staging chunks per wave (130 / 260)

  const int lane = threadIdx.x & 63, wave = threadIdx.x >> 6;
  const int l15 = lane & 15, q = lane >> 4;
  const int mw = wave >> 1, nw = wave & 1;
  const int y0 = blockIdx.x * ROWS, xt = blockIdx.y, b = blockIdx.z;
  __shared__ __align__(16) char smem[3 * ROWB];
  const __bf16* plane = in + (size_t)b * PADPLANE * CIN;

  // stage one padded-row window (130 px) into an LDS row slot
  auto stage = [&](int pr, char* lrow) {
    const char* g = (const char*)(plane + ((size_t)pr * PADW + xt * 128) * CIN);
    const int base = wave * PWCH;
    #pragma unroll
    for (int j = 0; j < PWCH / 64; j++) {
      int c = base + j * 64 + lane;
      gl_lds(g + (size_t)swz(c) * 16, lrow + (base + j * 64) * 16);
    }
    if (lane < (PWCH % 64)) {
      int c = base + (PWCH / 64) * 64 + lane;
      gl_lds(g + (size_t)swz(c) * 16, lrow + (base + (PWCH / 64) * 64) * 16);
    }
  };

  // hoist B fragments: couts nw*(COUT/2) + nt*16 + l15, all taps/k-chunks
  v8bf breg[9][KB * NT];
  #pragma unroll
  for (int tap = 0; tap < 9; tap++)
    #pragma unroll
    for (int kb = 0; kb < KB; kb++)
      #pragma unroll
      for (int nt = 0; nt < NT; nt++)
        breg[tap][kb * NT + nt] = *(const v8bf*)(Bt
            + (size_t)(nw * (COUT / 2) + nt * 16 + l15) * K9
            + tap * CIN + kb * 32 + q * 8);

  #pragma unroll
  for (int r = 0; r < 3; r++) stage(y0 + r, smem + r * ROWB);
  __syncthreads();

  for (int i = 0; i < ROWS; i++) {
    v4f acc[4][NT];
    #pragma unroll
    for (int nt = 0; nt < NT; nt++) {
      float bv = bias[nw * (COUT / 2) + nt * 16 + l15];
      #pragma unroll
      for (int mt = 0; mt < 4; mt++) acc[mt][nt] = (v4f){bv, bv, bv, bv};
    }
    #pragma unroll
    for (int tap = 0; tap < 9; tap++) {
      const int dy = tap / 3, dx = tap % 3;
      const char* srow = smem + ((i + dy) % 3) * ROWB;
      #pragma unroll
      for (int kb = 0; kb < KB; kb++) {
        v8bf af[4];
        #pragma unroll
        for (int mt = 0; mt < 4; mt++) {
          int p = mw * 64 + mt * 16 + l15 + dx;        // 0..129
          int G = p * CP + kb * 4 + q;                 // logical chunk
          af[mt] = *(const v8bf*)(srow + (size_t)swz(G) * 16);
        }
        #pragma unroll
        for (int mt = 0; mt < 4; mt++)
          #pragma unroll
          for (int nt = 0; nt < NT; nt++)
            acc[mt][nt] = __builtin_amdgcn_mfma_f32_16x16x32_bf16(
                af[mt], breg[tap][kb * NT + nt], acc[mt][nt], 0, 0, 0);
      }
    }
    {
      size_t rb = ((size_t)b * PADPLANE + (size_t)(y0 + i + 1) * PADW
                   + xt * 128 + 1) * COUT;
      #pragma unroll
      for (int mt = 0; mt < 4; mt++) {
        #pragma unroll
        for (int r = 0; r < 4; r++) {
          size_t pa = rb + (size_t)(mw * 64 + mt * 16 + q * 4 + r) * COUT;
          #pragma unroll
          for (int nt = 0; nt < NT; nt++)
            out[pa + nw * (COUT / 2) + nt * 16 + l15] =
                (__bf16)fmaxf(acc[mt][nt][r], 0.f);
        }
      }
    }
    __syncthreads();                       // readers done with slot i%3
    if (i + 3 < ROWS + 2)
      stage(y0 + i + 3, smem + (i % 3) * ROWB);
    __syncthreads();                       // staged row visible
  }
}

// ---------------------------------------------------------------------------
// conv4 (32->1) row-streaming: thread = one x-column, block = 4 output rows.
// Each padded row is loaded ONCE (12x uint4) and contributes to up to 3
// rotating accumulators; only rows this block owns (static pruning).
// Fused epilogue: V_hat = (conv+b4)*sf ; outputs = H + V_hat.
// ---------------------------------------------------------------------------
#define C4ROWS 4
__global__ __launch_bounds__(256) void conv4_k(
    const __bf16* __restrict__ act3, const float* __restrict__ w4t,
    const float* __restrict__ b4, const float* __restrict__ sfp,
    float* __restrict__ dout)
{
  const int x = threadIdx.x, y0 = blockIdx.x * C4ROWS, b = blockIdx.y;
  const float b4v = b4[0], sf = sfp[0];
  const uint4* base = (const uint4*)(act3 + (size_t)b * PADPLANE * 32);
  float accs[3] = {b4v, b4v, b4v};

  #pragma unroll
  for (int t = 0; t < C4ROWS + 2; t++) {
    const int pr = y0 + t;                       // padded row index
    const uint4* rp = base + ((size_t)pr * PADW + x) * 4;   // 4 uint4 / px
    uint4 L[12];
    #pragma unroll
    for (int j = 0; j < 12; j++) L[j] = rp[j];
    #pragma unroll
    for (int j = 0; j < 12; j++) {
      const int dx = j >> 2, c0 = (j & 3) * 8;
      unsigned int uu[4] = {L[j].x, L[j].y, L[j].z, L[j].w};
      float f[8];
      #pragma unroll
      for (int k = 0; k < 4; k++) {
        f[2*k]   = __builtin_bit_cast(float, uu[k] << 16);
        f[2*k+1] = __builtin_bit_cast(float, uu[k] & 0xFFFF0000u);
      }
      #pragma unroll
      for (int dyp = 0; dyp < 3; dyp++) {
        if (dyp <= t && t - dyp < C4ROWS) {
          const int slot = (t - dyp) % 3;
          const float* wp = w4t + (dyp * 3 + dx) * 32 + c0;   // uniform
          #pragma unroll
          for (int k = 0; k < 8; k++)
            accs[slot] = fmaf(wp[k], f[k], accs[slot]);
        }
      }
    }
    if (t >= 2) {                                // output row y0+t-2 complete
      const int r = y0 + t - 2, slot = (t - 2) % 3;
      size_t p0 = ((size_t)b << 16) + (size_t)r * WIDTH + x;
      float vh = accs[slot] * sf;
      dout[p0]           = dout[524288 + p0] + vh;   // outputs = H + V_hat
      dout[2621440 + p0] = vh;                       // V_hat
      accs[slot] = b4v;
    }
  }
}

// ---------------------------------------------------------------------------
extern "C" void kernel_launch(void* const* d_in, const int* in_sizes, int n_in,
                              void* d_out, int out_size, void* d_ws, size_t ws_size,
                              hipStream_t stream) {
  const float* inputs = (const float*)d_in[0];
  const float* H0     = (const float*)d_in[1];
  const float* C0     = (const float*)d_in[2];
  const float* c2     = (const float*)d_in[3];
  const float* sf     = (const float*)d_in[4];
  const float* w1     = (const float*)d_in[5];
  const float* b1     = (const float*)d_in[6];
  const float* w2     = (const float*)d_in[7];
  const float* b2     = (const float*)d_in[8];
  const float* w3     = (const float*)d_in[9];
  const float* b3     = (const float*)d_in[10];
  const float* w4     = (const float*)d_in[11];
  const float* b4     = (const float*)d_in[12];
  float* out = (float*)d_out;
  float* ws  = (float*)d_ws;

  float*  vs   = ws;                               // 524288 fp32
  float*  w1t  = ws + 524288;                      // 288 fp32
  float*  w4t  = ws + 524576;                      // 288 fp32
  __bf16* B2t  = (__bf16*)(ws + 524864);           // 18432 bf16
  __bf16* B3t  = (__bf16*)(ws + 534080);           // 18432 bf16
  __bf16* act1 = (__bf16*)(ws + 543296);           // 8*66564*32 bf16
  __bf16* act2 = act1 + (size_t)8 * PADPLANE * 32; // 8*66564*64 bf16
  __bf16* act3 = act2 + (size_t)8 * PADPLANE * 64; // 8*66564*32 bf16

  prep_k<<<2048, 256, 0, stream>>>(inputs, H0, C0, c2, sf, out, vs);
  wtrans_k<<<147, 256, 0, stream>>>(w1, w2, w3, w4, w1t, B2t, B3t, w4t);
  zero_k<<<2056, 256, 0, stream>>>(act1, act2, act3);
  conv1_k<<<dim3(256, 8), 256, 0, stream>>>(vs, w1t, b1, act1);
  conv_lds_k<32, 64, 4><<<dim3(64, 2, 8), 256, 0, stream>>>(act1, B2t, b2, act2);
  conv_lds_k<64, 32, 4><<<dim3(64, 2, 8), 256, 0, stream>>>(act2, B3t, b3, act3);
  conv4_k<<<dim3(64, 8), 256, 0, stream>>>(act3, w4t, b4, sf, out);
}

// Round 8
// 187.789 us; speedup vs baseline: 4.9289x; 1.0231x over previous
//
#include <hip/hip_runtime.h>

#define PLANE 65536
#define WIDTH 256
#define PADW 258
#define PADPLANE 66564   // 258*258

typedef __bf16 v8bf __attribute__((ext_vector_type(8)));
typedef float  v4f  __attribute__((ext_vector_type(4)));

typedef const __attribute__((address_space(1))) unsigned int* gas_ptr;
typedef __attribute__((address_space(3))) unsigned int* las_ptr;

// async global->LDS, 16 B per lane; LDS dest = wave-uniform base + lane*16
__device__ __forceinline__ void gl_lds(const void* g, void* l) {
  __builtin_amdgcn_global_load_lds((gas_ptr)g, (las_ptr)l, 16, 0, 0);
}

// self-inverse 16B-chunk swizzle within 8-chunk groups: breaks power-of-2
// bank strides for both CIN=32 (4 chunks/px) and CIN=64 (8 chunks/px).
// Verified 0 LDS bank conflicts in rounds 6-7 PMC.
__device__ __forceinline__ int swz(int c) {
  return (c & ~7) | ((c & 7) ^ ((c >> 3) & 7));
}

__device__ __forceinline__ unsigned int pack2(float a, float b) {
  __bf16 ba = (__bf16)a, bb = (__bf16)b;
  unsigned short sa = __builtin_bit_cast(unsigned short, ba);
  unsigned short sb = __builtin_bit_cast(unsigned short, bb);
  return (unsigned int)sa | ((unsigned int)sb << 16);
}

// ---------------------------------------------------------------------------
// prep: V, C_new, H (Laplacian), and stage vs = V/sf (fp32, unpadded NCHW).
// ---------------------------------------------------------------------------
__global__ __launch_bounds__(256) void prep_k(
    const float* __restrict__ inputs, const float* __restrict__ H0,
    const float* __restrict__ C0, const float* __restrict__ c2p,
    const float* __restrict__ sfp, float* __restrict__ dout,
    float* __restrict__ vs)
{
  int p = blockIdx.x * 256 + threadIdx.x;      // 0 .. 524287
  int b = p >> 16;
  int i = p & 65535;
  int y = i >> 8;
  int x = i & 255;
  float in   = inputs[p];
  float h0   = H0[p];
  float c0a  = C0[b * 131072 + i];             // C0[:,0]
  float up    = (y > 0)   ? inputs[p - 256] : 0.f;
  float down  = (y < 255) ? inputs[p + 256] : 0.f;
  float left  = (x > 0)   ? inputs[p - 1]   : 0.f;
  float right = (x < 255) ? inputs[p + 1]   : 0.f;
  float lap = up + down + left + right - 4.f * in;
  float c2 = c2p[0];
  float sf = sfp[0];
  float Hv = 2.f * in - c0a + c2 * lap;
  float V  = in - h0;
  dout[524288 + p]  = Hv;                      // H
  dout[2097152 + p] = V;                       // V
  dout[1048576 + b * 131072 + i]         = in;   // C_new[:,0]
  dout[1048576 + b * 131072 + 65536 + i] = c0a;  // C_new[:,1]
  vs[p] = V / sf;                              // conv-chain input
}

// ---------------------------------------------------------------------------
// weight prep: w1t[tap][cout] fp32; B2t[cout][tap*32+cin] bf16;
//              B3t[cout][tap*64+cin] bf16; w4t[tap][cin] fp32.
// ---------------------------------------------------------------------------
__global__ __launch_bounds__(256) void wtrans_k(
    const float* __restrict__ w1, const float* __restrict__ w2,
    const float* __restrict__ w3, const float* __restrict__ w4,
    float* __restrict__ w1t, __bf16* __restrict__ B2t,
    __bf16* __restrict__ B3t, float* __restrict__ w4t)
{
  int t = blockIdx.x * 256 + threadIdx.x;
  if (t < 288) {                       // w1: [32][1][9] -> [tap][32]
    int tap = t >> 5, cout = t & 31;
    w1t[t] = w1[cout * 9 + tap];
  }
  int t2 = t - 288;
  if (t2 >= 0 && t2 < 18432) {         // 64 x 288
    int cout = t2 / 288, k = t2 % 288;
    int tap = k / 32, cin = k % 32;
    B2t[t2] = (__bf16)w2[cout * 288 + cin * 9 + tap];
  }
  int t3 = t - (288 + 18432);
  if (t3 >= 0 && t3 < 18432) {         // 32 x 576
    int cout = t3 / 576, k = t3 % 576;
    int tap = k / 64, cin = k % 64;
    B3t[t3] = (__bf16)w3[cout * 576 + cin * 9 + tap];
  }
  int t4 = t - (288 + 18432 + 18432);
  if (t4 >= 0 && t4 < 288) {           // w4: [1][32][9] -> [tap][32]
    int tap = t4 >> 5, cin = t4 & 31;
    w4t[t4] = w4[cin * 9 + tap];
  }
}

// ---------------------------------------------------------------------------
// zero the 1-px padding ring of act1/act2/act3 (ws is poisoned every call).
// ---------------------------------------------------------------------------
#define R1 (8 * 1028 * 16)
#define R2 (8 * 1028 * 32)
#define R3 (8 * 1028 * 16)
__global__ __launch_bounds__(256) void zero_k(
    __bf16* __restrict__ a1, __bf16* __restrict__ a2, __bf16* __restrict__ a3)
{
  int t = blockIdx.x * 256 + threadIdx.x;
  unsigned int* p; int C2, idx;
  if (t < R1)            { p = (unsigned int*)a1; C2 = 16; idx = t; }
  else if (t < R1 + R2)  { p = (unsigned int*)a2; C2 = 32; idx = t - R1; }
  else if (t < R1+R2+R3) { p = (unsigned int*)a3; C2 = 16; idx = t - R1 - R2; }
  else return;
  int ch = idx % C2;
  int pr = idx / C2;                 // 0 .. 8*1028-1
  int b = pr / 1028, r = pr % 1028;
  int y, x;
  if      (r < 258) { y = 0;           x = r; }
  else if (r < 516) { y = 257;         x = r - 258; }
  else if (r < 772) { y = r - 516 + 1; x = 0; }
  else              { y = r - 772 + 1; x = 257; }
  p[((size_t)b * PADPLANE + y * PADW + x) * C2 + ch] = 0;
}

// ---------------------------------------------------------------------------
// conv1: 1->32 fp32 vector, thread/pixel; writes act1 NHWC bf16 padded.
// ---------------------------------------------------------------------------
__global__ __launch_bounds__(256) void conv1_k(
    const float* __restrict__ vs, const float* __restrict__ w1t,
    const float* __restrict__ b1, __bf16* __restrict__ act1)
{
  int x = threadIdx.x, y = blockIdx.x, b = blockIdx.y;
  const float* ip = vs + ((size_t)b << 16) + y * WIDTH + x;
  float acc[32];
  #pragma unroll
  for (int i = 0; i < 32; i++) acc[i] = b1[i];
  #pragma unroll
  for (int tap = 0; tap < 9; tap++) {
    int dy = tap / 3 - 1, dx = tap % 3 - 1;
    int yy = y + dy, xx = x + dx;
    bool ok = (yy >= 0 && yy < 256 && xx >= 0 && xx < 256);
    float v = ok ? ip[dy * WIDTH + dx] : 0.f;
    const float* wp = w1t + tap * 32;           // uniform
    #pragma unroll
    for (int i = 0; i < 32; i++) acc[i] = fmaf(wp[i], v, acc[i]);
  }
  unsigned int u[16];
  #pragma unroll
  for (int j = 0; j < 16; j++)
    u[j] = pack2(fmaxf(acc[2*j], 0.f), fmaxf(acc[2*j+1], 0.f));
  size_t pa = ((size_t)b * PADPLANE + (y+1) * PADW + (x+1)) * 32;
  uint4* op = reinterpret_cast<uint4*>(act1 + pa);
  #pragma unroll
  for (int j = 0; j < 4; j++)
    op[j] = make_uint4(u[4*j], u[4*j+1], u[4*j+2], u[4*j+3]);
}

// ---------------------------------------------------------------------------
// conv2 (32->64), A-reuse-maximized: block = 4 waves = 4 disjoint M-quarters
// of a 128-px x-tile; EACH wave holds ALL 64 couts' B-fragments in registers
// (NT=4, 36 v8bf). A-read reuse = 4 MFMA / ds_read_b128 = 32 MAC/B > the
// 22.9 MAC/B LDS-feed threshold -> MFMA-bound. Ring of 3 act1 rows in LDS.
// ---------------------------------------------------------------------------
#define C2ROWB 8320   // 130 px * 32 ch * 2 B
template<int ROWS>
__global__ __launch_bounds__(256, 2) void conv2_k(
    const __bf16* __restrict__ in, const __bf16* __restrict__ Bt,
    const float* __restrict__ bias, __bf16* __restrict__ out)
{
  const int lane = threadIdx.x & 63, wave = threadIdx.x >> 6;
  const int l15 = lane & 15, q = lane >> 4;
  const int y0 = blockIdx.x * ROWS, xt = blockIdx.y, b = blockIdx.z;
  const int x0 = xt * 128;
  __shared__ __align__(16) char smem[3 * C2ROWB];
  const __bf16* plane = in + (size_t)b * PADPLANE * 32;

  auto stage = [&](int pr, char* lrow) {       // 130 px = 520 chunks, 130/wave
    const char* g = (const char*)(plane + ((size_t)pr * PADW + x0) * 32);
    const int base = wave * 130;
    #pragma unroll
    for (int j = 0; j < 2; j++) {
      int c = base + j * 64 + lane;
      gl_lds(g + (size_t)swz(c) * 16, lrow + (base + j * 64) * 16);
    }
    if (lane < 2) {
      int c = base + 128 + lane;
      gl_lds(g + (size_t)swz(c) * 16, lrow + (base + 128) * 16);
    }
  };

  // all 64 couts' B-fragments in registers: 36 v8bf
  v8bf breg[9][4];
  #pragma unroll
  for (int tap = 0; tap < 9; tap++)
    #pragma unroll
    for (int nt = 0; nt < 4; nt++)
      breg[tap][nt] = *(const v8bf*)(Bt + (size_t)(nt * 16 + l15) * 288
                                        + tap * 32 + q * 8);
  float bv[4];
  #pragma unroll
  for (int nt = 0; nt < 4; nt++) bv[nt] = bias[nt * 16 + l15];

  #pragma unroll
  for (int r = 0; r < 3; r++) stage(y0 + r, smem + r * C2ROWB);
  __syncthreads();

  for (int i = 0; i < ROWS; i++) {
    v4f acc[2][4];
    #pragma unroll
    for (int mt = 0; mt < 2; mt++)
      #pragma unroll
      for (int nt = 0; nt < 4; nt++)
        acc[mt][nt] = (v4f){bv[nt], bv[nt], bv[nt], bv[nt]};

    #pragma unroll
    for (int tap = 0; tap < 9; tap++) {
      const int dy = tap / 3, dx = tap % 3;
      const char* srow = smem + ((i + dy) % 3) * C2ROWB;
      v8bf af[2];
      #pragma unroll
      for (int mt = 0; mt < 2; mt++) {
        int P = wave * 32 + mt * 16 + l15 + dx;      // 0..129
        af[mt] = *(const v8bf*)(srow + (size_t)swz(P * 4 + q) * 16);
      }
      #pragma unroll
      for (int mt = 0; mt < 2; mt++)
        #pragma unroll
        for (int nt = 0; nt < 4; nt++)
          acc[mt][nt] = __builtin_amdgcn_mfma_f32_16x16x32_bf16(
              af[mt], breg[tap][nt], acc[mt][nt], 0, 0, 0);
    }
    {
      size_t rb = ((size_t)b * PADPLANE + (size_t)(y0 + i + 1) * PADW
                   + x0 + 1) * 64;
      #pragma unroll
      for (int mt = 0; mt < 2; mt++) {
        #pragma unroll
        for (int r = 0; r < 4; r++) {
          size_t pa = rb + (size_t)(wave * 32 + mt * 16 + q * 4 + r) * 64;
          #pragma unroll
          for (int nt = 0; nt < 4; nt++)
            out[pa + nt * 16 + l15] = (__bf16)fmaxf(acc[mt][nt][r], 0.f);
        }
      }
    }
    __syncthreads();
    if (i + 3 < ROWS + 2)
      stage(y0 + i + 3, smem + (i % 3) * C2ROWB);
    __syncthreads();
  }
}

// ---------------------------------------------------------------------------
// conv3 (64->32), A-reuse-maximized: NT=2 (all 32 couts in registers) PLUS
// row-pairing: a ring of 4 act2 rows serves TWO output rows per iteration --
// each A-fragment feeds taps dy (row r0) and dy-1 (row r1): 24 MAC per LDS
// byte -> MFMA-bound. Block = 4 waves = 4 M-quarters of a 128-px x-tile.
// ---------------------------------------------------------------------------
#define C3ROWB 16640   // 130 px * 64 ch * 2 B
template<int ROWS>     // even
__global__ __launch_bounds__(256, 2) void conv3_k(
    const __bf16* __restrict__ in, const __bf16* __restrict__ Bt,
    const float* __restrict__ bias, __bf16* __restrict__ out)
{
  const int lane = threadIdx.x & 63, wave = threadIdx.x >> 6;
  const int l15 = lane & 15, q = lane >> 4;
  const int y0 = blockIdx.x * ROWS, xt = blockIdx.y, b = blockIdx.z;
  const int x0 = xt * 128;
  __shared__ __align__(16) char smem[4 * C3ROWB];
  const __bf16* plane = in + (size_t)b * PADPLANE * 64;

  auto stage = [&](int pr, char* lrow) {       // 130 px = 1040 chunks, 260/wave
    const char* g = (const char*)(plane + ((size_t)pr * PADW + x0) * 64);
    const int base = wave * 260;
    #pragma unroll
    for (int j = 0; j < 4; j++) {
      int c = base + j * 64 + lane;
      gl_lds(g + (size_t)swz(c) * 16, lrow + (base + j * 64) * 16);
    }
    if (lane < 4) {
      int c = base + 256 + lane;
      gl_lds(g + (size_t)swz(c) * 16, lrow + (base + 256) * 16);
    }
  };

  // all 32 couts' B-fragments in registers: 36 v8bf
  v8bf breg[9][2][2];                          // tap, kb, nt
  #pragma unroll
  for (int tap = 0; tap < 9; tap++)
    #pragma unroll
    for (int kb = 0; kb < 2; kb++)
      #pragma unroll
      for (int nt = 0; nt < 2; nt++)
        breg[tap][kb][nt] = *(const v8bf*)(Bt + (size_t)(nt * 16 + l15) * 576
                                              + tap * 64 + kb * 32 + q * 8);
  float bv[2] = {bias[l15], bias[16 + l15]};

  #pragma unroll
  for (int r = 0; r < 4; r++) stage(y0 + r, smem + r * C3ROWB);
  __syncthreads();

  for (int ps = 0; ps < ROWS / 2; ps++) {      // output rows r0=y0+2ps, r0+1
    v4f acc[2][2][2];                          // rr, mt, nt
    #pragma unroll
    for (int rr = 0; rr < 2; rr++)
      #pragma unroll
      for (int mt = 0; mt < 2; mt++)
        #pragma unroll
        for (int nt = 0; nt < 2; nt++)
          acc[rr][mt][nt] = (v4f){bv[nt], bv[nt], bv[nt], bv[nt]};

    #pragma unroll
    for (int t = 0; t < 4; t++) {              // act2 ring row = padded y0+2ps+t
      const char* srow = smem + ((2 * ps + t) & 3) * C3ROWB;
      #pragma unroll
      for (int dx = 0; dx < 3; dx++) {
        #pragma unroll
        for (int kb = 0; kb < 2; kb++) {
          v8bf af[2];
          #pragma unroll
          for (int mt = 0; mt < 2; mt++) {
            int P = wave * 32 + mt * 16 + l15 + dx;   // 0..129
            af[mt] = *(const v8bf*)(srow + (size_t)swz(P * 8 + kb * 4 + q) * 16);
          }
          #pragma unroll
          for (int mt = 0; mt < 2; mt++)
            #pragma unroll
            for (int nt = 0; nt < 2; nt++) {
              if (t <= 2)                       // row r0, tap dy = t
                acc[0][mt][nt] = __builtin_amdgcn_mfma_f32_16x16x32_bf16(
                    af[mt], breg[t * 3 + dx][kb][nt], acc[0][mt][nt], 0, 0, 0);
              if (t >= 1)                       // row r1, tap dy = t-1
                acc[1][mt][nt] = __builtin_amdgcn_mfma_f32_16x16x32_bf16(
                    af[mt], breg[(t - 1) * 3 + dx][kb][nt], acc[1][mt][nt],
                    0, 0, 0);
            }
        }
      }
    }
    {
      #pragma unroll
      for (int rr = 0; rr < 2; rr++) {
        size_t rb = ((size_t)b * PADPLANE
                     + (size_t)(y0 + 2 * ps + rr + 1) * PADW + x0 + 1) * 32;
        #pragma unroll
        for (int mt = 0; mt < 2; mt++) {
          #pragma unroll
          for (int r = 0; r < 4; r++) {
            size_t pa = rb + (size_t)(wave * 32 + mt * 16 + q * 4 + r) * 32;
            #pragma unroll
            for (int nt = 0; nt < 2; nt++)
              out[pa + nt * 16 + l15] = (__bf16)fmaxf(acc[rr][mt][nt][r], 0.f);
          }
        }
      }
    }
    __syncthreads();
    if (ps + 1 < ROWS / 2) {                   // stage rows 2ps+4, 2ps+5
      stage(y0 + 2 * ps + 4, smem + ((2 * ps) & 3) * C3ROWB);
      stage(y0 + 2 * ps + 5, smem + ((2 * ps + 1) & 3) * C3ROWB);
    }
    __syncthreads();
  }
}

// ---------------------------------------------------------------------------
// conv4 (32->1) row-streaming: thread = one x-column, block = 4 output rows.
// Each padded row is loaded ONCE (12x uint4) and contributes to up to 3
// rotating accumulators; only rows this block owns (static pruning).
// Fused epilogue: V_hat = (conv+b4)*sf ; outputs = H + V_hat.
// ---------------------------------------------------------------------------
#define C4ROWS 4
__global__ __launch_bounds__(256) void conv4_k(
    const __bf16* __restrict__ act3, const float* __restrict__ w4t,
    const float* __restrict__ b4, const float* __restrict__ sfp,
    float* __restrict__ dout)
{
  const int x = threadIdx.x, y0 = blockIdx.x * C4ROWS, b = blockIdx.y;
  const float b4v = b4[0], sf = sfp[0];
  const uint4* base = (const uint4*)(act3 + (size_t)b * PADPLANE * 32);
  float accs[3] = {b4v, b4v, b4v};

  #pragma unroll
  for (int t = 0; t < C4ROWS + 2; t++) {
    const int pr = y0 + t;                       // padded row index
    const uint4* rp = base + ((size_t)pr * PADW + x) * 4;   // 4 uint4 / px
    uint4 L[12];
    #pragma unroll
    for (int j = 0; j < 12; j++) L[j] = rp[j];
    #pragma unroll
    for (int j = 0; j < 12; j++) {
      const int dx = j >> 2, c0 = (j & 3) * 8;
      unsigned int uu[4] = {L[j].x, L[j].y, L[j].z, L[j].w};
      float f[8];
      #pragma unroll
      for (int k = 0; k < 4; k++) {
        f[2*k]   = __builtin_bit_cast(float, uu[k] << 16);
        f[2*k+1] = __builtin_bit_cast(float, uu[k] & 0xFFFF0000u);
      }
      #pragma unroll
      for (int dyp = 0; dyp < 3; dyp++) {
        if (dyp <= t && t - dyp < C4ROWS) {
          const int slot = (t - dyp) % 3;
          const float* wp = w4t + (dyp * 3 + dx) * 32 + c0;   // uniform
          #pragma unroll
          for (int k = 0; k < 8; k++)
            accs[slot] = fmaf(wp[k], f[k], accs[slot]);
        }
      }
    }
    if (t >= 2) {                                // output row y0+t-2 complete
      const int r = y0 + t - 2, slot = (t - 2) % 3;
      size_t p0 = ((size_t)b << 16) + (size_t)r * WIDTH + x;
      float vh = accs[slot] * sf;
      dout[p0]           = dout[524288 + p0] + vh;   // outputs = H + V_hat
      dout[2621440 + p0] = vh;                       // V_hat
      accs[slot] = b4v;
    }
  }
}

// ---------------------------------------------------------------------------
extern "C" void kernel_launch(void* const* d_in, const int* in_sizes, int n_in,
                              void* d_out, int out_size, void* d_ws, size_t ws_size,
                              hipStream_t stream) {
  const float* inputs = (const float*)d_in[0];
  const float* H0     = (const float*)d_in[1];
  const float* C0     = (const float*)d_in[2];
  const float* c2     = (const float*)d_in[3];
  const float* sf     = (const float*)d_in[4];
  const float* w1     = (const float*)d_in[5];
  const float* b1     = (const float*)d_in[6];
  const float* w2     = (const float*)d_in[7];
  const float* b2     = (const float*)d_in[8];
  const float* w3     = (const float*)d_in[9];
  const float* b3     = (const float*)d_in[10];
  const float* w4     = (const float*)d_in[11];
  const float* b4     = (const float*)d_in[12];
  float* out = (float*)d_out;
  float* ws  = (float*)d_ws;

  float*  vs   = ws;                               // 524288 fp32
  float*  w1t  = ws + 524288;                      // 288 fp32
  float*  w4t  = ws + 524576;                      // 288 fp32
  __bf16* B2t  = (__bf16*)(ws + 524864);           // 18432 bf16
  __bf16* B3t  = (__bf16*)(ws + 534080);           // 18432 bf16
  __bf16* act1 = (__bf16*)(ws + 543296);           // 8*66564*32 bf16
  __bf16* act2 = act1 + (size_t)8 * PADPLANE * 32; // 8*66564*64 bf16
  __bf16* act3 = act2 + (size_t)8 * PADPLANE * 64; // 8*66564*32 bf16

  prep_k<<<2048, 256, 0, stream>>>(inputs, H0, C0, c2, sf, out, vs);
  wtrans_k<<<147, 256, 0, stream>>>(w1, w2, w3, w4, w1t, B2t, B3t, w4t);
  zero_k<<<2056, 256, 0, stream>>>(act1, act2, act3);
  conv1_k<<<dim3(256, 8), 256, 0, stream>>>(vs, w1t, b1, act1);
  conv2_k<8><<<dim3(32, 2, 8), 256, 0, stream>>>(act1, B2t, b2, act2);
  conv3_k<8><<<dim3(32, 2, 8), 256, 0, stream>>>(act2, B3t, b3, act3);
  conv4_k<<<dim3(64, 8), 256, 0, stream>>>(act3, w4t, b4, sf, out);
}